// Round 1
// baseline (11421.722 us; speedup 1.0000x reference)
//
#include <hip/hip_runtime.h>
#include <stdint.h>
#include <stddef.h>

// Problem constants (test=False shapes)
#define E_DIM 1024
#define B_SZ  16
#define N_SEQ 1024
#define L_NUM 12
#define ACT_D 640   // DIM*ACT_NUM
#define ADIM_ 10

typedef unsigned short u16;
typedef __attribute__((ext_vector_type(8))) short bf16x8;
typedef __attribute__((ext_vector_type(4))) float f32x4;

__device__ __forceinline__ u16 f2bf(float x) {
  union { float f; unsigned int u; } c; c.f = x;
  unsigned int r = c.u + 0x7fffu + ((c.u >> 16) & 1u);
  return (u16)(r >> 16);
}
__device__ __forceinline__ float bf2f(u16 h) {
  union { unsigned int u; float f; } c; c.u = ((unsigned int)h) << 16;
  return c.f;
}

struct us4 { u16 x, y, z, w; };

#define GLD16(gsrc, ldst) __builtin_amdgcn_global_load_lds( \
    (const __attribute__((address_space(1))) void*)(gsrc),  \
    (__attribute__((address_space(3))) void*)(ldst), 16, 0, 0)

// ---------------------------------------------------------------------------
// Error-compensated split-bf16 MFMA NT GEMM.
//   C[M,N] = A[M,K] @ B[N,K]^T  computed as  Ah@Bh^T + Ah@Bl^T + Al@Bh^T
// where X = Xh + Xl (both bf16, lo = residual). fp32 accumulate in AGPRs.
// Tile 128x128, BK=32, 256 threads (4 waves as 2x2 of 64x64), 4x4 frags of
// mfma_f32_16x16x32_bf16 per wave. global_load_lds(16B) staging, linear LDS
// [128][32] per operand tile (m97 structure).
// MODE 0: full grid (bid = tm*tilesN+tn), full K
// MODE 1: lower-triangular 128-tiles only (attention S)
// MODE 2: full grid, K capped at (tm+1)*128 (causal S@V)
// EPI  0: Co = acc (fp32)
// EPI  1: split acc -> Ch/Cl (bf16 hi/lo)
// EPI  2: split relu(acc + bias[col])           (MLP hidden)
// EPI  3: split causal: relu(acc)/(row+1), col<=row else 0   (scores S)
// EPI  4: Co = acc + bias[col] (fp32)           (MLP out)
// M,N multiples of 128; K multiple of 32.
// ---------------------------------------------------------------------------
#define TM 128
#define TN 128
#define TK 32

template<int MODE, int EPI>
__global__ __launch_bounds__(256)
void gemm_nt_mfma(const u16* __restrict__ Ah, const u16* __restrict__ Al,
                  const u16* __restrict__ Bh, const u16* __restrict__ Bl,
                  float* __restrict__ Co, u16* __restrict__ Ch, u16* __restrict__ Cl,
                  const float* __restrict__ bias,
                  int K, int lda, int ldb, int ldc, int tilesN,
                  long long sA, long long sB, long long sC)
{
  __shared__ u16 smem[4 * TM * TK];   // Ah | Al | Bh | Bl tiles, 8 KB each

  const int tid = threadIdx.x;
  const int bat = blockIdx.y;
  Ah += bat * sA; Al += bat * sA;
  Bh += bat * sB; Bl += bat * sB;

  int tm, tn;
  if (MODE == 1) {
    int t = blockIdx.x, m = 0;
    while ((m + 1) * (m + 2) / 2 <= t) m++;
    tm = m; tn = t - m * (m + 1) / 2;
  } else {
    tm = blockIdx.x / tilesN;
    tn = blockIdx.x % tilesN;
  }
  int kend = K;
  if (MODE == 2) { int c = (tm + 1) * TM; kend = (c < K) ? c : K; }

  // staging: 512 16B-chunks per tile, 2 per thread per tile.
  // chunk c -> row c>>2, k-part (c&3)*8 elems; LDS dst linear (lane-order).
  const int c0 = tid, c1 = tid + 256;
  const int r0 = c0 >> 2, p0 = (c0 & 3) * 8;
  const int r1 = c1 >> 2, p1 = (c1 & 3) * 8;
  const u16* gAh0 = Ah + ((long long)tm * TM + r0) * lda + p0;
  const u16* gAh1 = Ah + ((long long)tm * TM + r1) * lda + p1;
  const u16* gAl0 = Al + ((long long)tm * TM + r0) * lda + p0;
  const u16* gAl1 = Al + ((long long)tm * TM + r1) * lda + p1;
  const u16* gBh0 = Bh + ((long long)tn * TN + r0) * ldb + p0;
  const u16* gBh1 = Bh + ((long long)tn * TN + r1) * ldb + p1;
  const u16* gBl0 = Bl + ((long long)tn * TN + r0) * ldb + p0;
  const u16* gBl1 = Bl + ((long long)tn * TN + r1) * ldb + p1;
  u16* dst0 = smem + c0 * 8;
  u16* dst1 = smem + c1 * 8;

  // fragment read offsets (u16 units); row stride 32, 16B-aligned reads
  const int lane = tid & 63;
  const int w = tid >> 6, wr = w >> 1, wc = w & 1;
  const int fr = lane & 15;
  const int kq = (lane >> 4) * 8;
  const int aoff = (wr * 64 + fr) * TK + kq;
  const int boff = (wc * 64 + fr) * TK + kq;

  f32x4 acc[4][4];
  #pragma unroll
  for (int m = 0; m < 4; m++)
    #pragma unroll
    for (int n = 0; n < 4; n++) acc[m][n] = (f32x4){0.f, 0.f, 0.f, 0.f};

  for (int k0 = 0; k0 < kend; k0 += TK) {
    __syncthreads();   // prior iteration's LDS reads done before overwrite
    GLD16(gAh0, dst0);          GLD16(gAh1, dst1);
    GLD16(gAl0, dst0 + 4096);   GLD16(gAl1, dst1 + 4096);
    GLD16(gBh0, dst0 + 8192);   GLD16(gBh1, dst1 + 8192);
    GLD16(gBl0, dst0 + 12288);  GLD16(gBl1, dst1 + 12288);
    gAh0 += TK; gAh1 += TK; gAl0 += TK; gAl1 += TK;
    gBh0 += TK; gBh1 += TK; gBl0 += TK; gBl1 += TK;
    __syncthreads();   // compiler drains vmcnt(0) before s_barrier

    bf16x8 ah[4], al[4], bh[4], bl[4];
    #pragma unroll
    for (int m = 0; m < 4; m++) ah[m] = *(const bf16x8*)(smem + aoff + m * 512);
    #pragma unroll
    for (int n = 0; n < 4; n++) bh[n] = *(const bf16x8*)(smem + 8192 + boff + n * 512);
    #pragma unroll
    for (int m = 0; m < 4; m++)
      #pragma unroll
      for (int n = 0; n < 4; n++)
        acc[m][n] = __builtin_amdgcn_mfma_f32_16x16x32_bf16(ah[m], bh[n], acc[m][n], 0, 0, 0);
    #pragma unroll
    for (int n = 0; n < 4; n++) bl[n] = *(const bf16x8*)(smem + 12288 + boff + n * 512);
    #pragma unroll
    for (int m = 0; m < 4; m++)
      #pragma unroll
      for (int n = 0; n < 4; n++)
        acc[m][n] = __builtin_amdgcn_mfma_f32_16x16x32_bf16(ah[m], bl[n], acc[m][n], 0, 0, 0);
    #pragma unroll
    for (int m = 0; m < 4; m++) al[m] = *(const bf16x8*)(smem + 4096 + aoff + m * 512);
    #pragma unroll
    for (int m = 0; m < 4; m++)
      #pragma unroll
      for (int n = 0; n < 4; n++)
        acc[m][n] = __builtin_amdgcn_mfma_f32_16x16x32_bf16(al[m], bh[n], acc[m][n], 0, 0, 0);
  }

  // epilogue: C/D layout col = lane&15, row = (lane>>4)*4 + reg  [m89/m91]
  if (Co) Co += bat * sC;
  if (Ch) { Ch += bat * sC; Cl += bat * sC; }
  #pragma unroll
  for (int m = 0; m < 4; m++) {
    #pragma unroll
    for (int r = 0; r < 4; r++) {
      const long long row = (long long)tm * TM + wr * 64 + m * 16 + (lane >> 4) * 4 + r;
      #pragma unroll
      for (int n = 0; n < 4; n++) {
        const long long col = (long long)tn * TN + wc * 64 + n * 16 + (lane & 15);
        float v = acc[m][n][r];
        if (EPI == 2) { v += bias[col]; v = v > 0.f ? v : 0.f; }
        if (EPI == 4) { v += bias[col]; }
        if (EPI == 3) {
          v = v > 0.f ? v : 0.f;
          v = (col <= row) ? v / (float)(row + 1) : 0.f;
        }
        const long long idx = row * (long long)ldc + col;
        if (EPI == 0 || EPI == 4) {
          Co[idx] = v;
        } else {
          u16 h = f2bf(v);
          Ch[idx] = h;
          Cl[idx] = f2bf(v - bf2f(h));
        }
      }
    }
  }
}

// ---------------------------------------------------------------------------
// Transpose fp32 W -> bf16 hi/lo:  dh/dl[c][r] = split(src[r][c])
// ---------------------------------------------------------------------------
__global__ __launch_bounds__(256)
void transpose_split(const float* __restrict__ src, u16* __restrict__ dh,
                     u16* __restrict__ dl, int rows, int cols)
{
  __shared__ float tile[32][33];
  const int c0 = blockIdx.x * 32, r0 = blockIdx.y * 32;
  const int tx = threadIdx.x & 31, ty = threadIdx.x >> 5;  // 32x8
  #pragma unroll
  for (int i = ty; i < 32; i += 8)
    tile[i][tx] = src[(long long)(r0 + i) * cols + c0 + tx];
  __syncthreads();
  #pragma unroll
  for (int i = ty; i < 32; i += 8) {
    const float v = tile[tx][i];
    const u16 h = f2bf(v);
    const long long idx = (long long)(c0 + i) * rows + r0 + tx;
    dh[idx] = h;
    dl[idx] = f2bf(v - bf2f(h));
  }
}

// ---------------------------------------------------------------------------
// Residual add + LayerNorm: x = Hs + delta; Hs = LN(x)*g + b; also bf16 split
// ---------------------------------------------------------------------------
__global__ __launch_bounds__(256)
void resid_ln(float* __restrict__ Hs, const float* __restrict__ delta,
              const float* __restrict__ g, const float* __restrict__ bta,
              u16* __restrict__ oh, u16* __restrict__ ol)
{
  __shared__ float red[8];
  const long long row = blockIdx.x;
  float* hp = Hs + row * E_DIM;
  const float* dp = delta + row * E_DIM;
  const int tid = threadIdx.x;
  const int e = tid * 4;

  float4 h = *(const float4*)(hp + e);
  float4 d = *(const float4*)(dp + e);
  float x0 = h.x + d.x, x1 = h.y + d.y, x2 = h.z + d.z, x3 = h.w + d.w;
  float s = x0 + x1 + x2 + x3;
  float q = x0 * x0 + x1 * x1 + x2 * x2 + x3 * x3;
  #pragma unroll
  for (int o = 32; o > 0; o >>= 1) { s += __shfl_down(s, o); q += __shfl_down(q, o); }
  const int lane = tid & 63, wv = tid >> 6;
  if (lane == 0) { red[wv] = s; red[wv + 4] = q; }
  __syncthreads();
  const float st = red[0] + red[1] + red[2] + red[3];
  const float qt = red[4] + red[5] + red[6] + red[7];
  const float mu = st * (1.0f / E_DIM);
  const float var = qt * (1.0f / E_DIM) - mu * mu;
  const float rstd = rsqrtf(var + 1e-5f);

  float4 gg = *(const float4*)(g + e);
  float4 bb = *(const float4*)(bta + e);
  float4 y;
  y.x = (x0 - mu) * rstd * gg.x + bb.x;
  y.y = (x1 - mu) * rstd * gg.y + bb.y;
  y.z = (x2 - mu) * rstd * gg.z + bb.z;
  y.w = (x3 - mu) * rstd * gg.w + bb.w;
  *(float4*)(hp + e) = y;

  us4 hv, lv;
  hv.x = f2bf(y.x); lv.x = f2bf(y.x - bf2f(hv.x));
  hv.y = f2bf(y.y); lv.y = f2bf(y.y - bf2f(hv.y));
  hv.z = f2bf(y.z); lv.z = f2bf(y.z - bf2f(hv.z));
  hv.w = f2bf(y.w); lv.w = f2bf(y.w - bf2f(hv.w));
  *(us4*)(oh + row * E_DIM + e) = hv;
  *(us4*)(ol + row * E_DIM + e) = lv;
}

// ---------------------------------------------------------------------------
// Embedding: A_emb[b,e] = act[b,:640] @ W_emb[:640, e]
// ---------------------------------------------------------------------------
__global__ __launch_bounds__(256)
void emb_dot(const float* __restrict__ act, const float* __restrict__ Wemb,
             float* __restrict__ Aemb)
{
  const int e = blockIdx.x * 256 + threadIdx.x;
  const int b = blockIdx.y;
  const float* ab = act + b * ACT_D;
  float s = 0.f;
  for (int d = 0; d < ACT_D; d++)
    s = fmaf(ab[d], Wemb[(long long)d * E_DIM + e], s);
  Aemb[b * E_DIM + e] = s;
}

// Hs[b,i,:] = (i even ? A_emb[b] : 0) + b_emb + W_emb[651] + (i+1)*W_emb[652] + wpe[i]
__global__ __launch_bounds__(256)
void emb_fill(const float* __restrict__ Aemb, const float* __restrict__ Wemb,
              const float* __restrict__ bemb, const float* __restrict__ wpe,
              float* __restrict__ Hs, u16* __restrict__ oh, u16* __restrict__ ol)
{
  const int i = blockIdx.x, b = blockIdx.y;
  const int e = threadIdx.x * 4;
  float4 a;
  if ((i & 1) == 0) a = *(const float4*)(Aemb + b * E_DIM + e);
  else { a.x = 0.f; a.y = 0.f; a.z = 0.f; a.w = 0.f; }
  float4 be = *(const float4*)(bemb + e);
  float4 w1 = *(const float4*)(Wemb + 651LL * E_DIM + e);
  float4 w2 = *(const float4*)(Wemb + 652LL * E_DIM + e);
  float4 pw = *(const float4*)(wpe + (long long)i * E_DIM + e);
  const float pos = (float)(i + 1);
  float4 y;
  y.x = a.x + be.x + w1.x + pos * w2.x + pw.x;
  y.y = a.y + be.y + w1.y + pos * w2.y + pw.y;
  y.z = a.z + be.z + w1.z + pos * w2.z + pw.z;
  y.w = a.w + be.w + w1.w + pos * w2.w + pw.w;
  const long long row = (long long)b * N_SEQ + i;
  *(float4*)(Hs + row * E_DIM + e) = y;

  us4 hv, lv;
  hv.x = f2bf(y.x); lv.x = f2bf(y.x - bf2f(hv.x));
  hv.y = f2bf(y.y); lv.y = f2bf(y.y - bf2f(hv.y));
  hv.z = f2bf(y.z); lv.z = f2bf(y.z - bf2f(hv.z));
  hv.w = f2bf(y.w); lv.w = f2bf(y.w - bf2f(hv.w));
  *(us4*)(oh + row * E_DIM + e) = hv;
  *(us4*)(ol + row * E_DIM + e) = lv;
}

// ---------------------------------------------------------------------------
// Final head: out[b,h,:] = Hs[b,2h,:] @ W_pred + b_pred
// ---------------------------------------------------------------------------
__global__ __launch_bounds__(256)
void pred_k(const float* __restrict__ Hs, const float* __restrict__ Wp,
            const float* __restrict__ bp, float* __restrict__ out)
{
  __shared__ float part[4][ADIM_];
  const int h = blockIdx.x, b = blockIdx.y;
  const long long row = (long long)b * N_SEQ + 2 * h;
  const float* x = Hs + row * E_DIM;
  float acc[ADIM_];
  #pragma unroll
  for (int a = 0; a < ADIM_; a++) acc[a] = 0.f;
  for (int e = threadIdx.x; e < E_DIM; e += 256) {
    const float xv = x[e];
    const float* w = Wp + e * ADIM_;
    #pragma unroll
    for (int a = 0; a < ADIM_; a++) acc[a] = fmaf(xv, w[a], acc[a]);
  }
  const int lane = threadIdx.x & 63, wv = threadIdx.x >> 6;
  #pragma unroll
  for (int a = 0; a < ADIM_; a++)
    #pragma unroll
    for (int o = 32; o > 0; o >>= 1) acc[a] += __shfl_down(acc[a], o);
  if (lane == 0)
    #pragma unroll
    for (int a = 0; a < ADIM_; a++) part[wv][a] = acc[a];
  __syncthreads();
  if (threadIdx.x < ADIM_) {
    const int a = threadIdx.x;
    out[((long long)b * (N_SEQ / 2) + h) * ADIM_ + a] =
        part[0][a] + part[1][a] + part[2][a] + part[3][a] + bp[a];
  }
}

// Diagnostic sentinel: unambiguous "workspace too small" signature
__global__ __launch_bounds__(256)
void fill_sentinel(float* p, int n, float v)
{
  int i = blockIdx.x * 256 + threadIdx.x;
  if (i < n) p[i] = v;
}

// ---------------------------------------------------------------------------
extern "C" void kernel_launch(void* const* d_in, const int* in_sizes, int n_in,
                              void* d_out, int out_size, void* d_ws, size_t ws_size,
                              hipStream_t stream)
{
  const float* act  = (const float*)d_in[0];
  // d_in[1] context_rewards: numerically unused by the reference
  const float* wpe  = (const float*)d_in[2];
  const float* Wemb = (const float*)d_in[3];
  const float* bemb = (const float*)d_in[4];
  const float* Wq   = (const float*)d_in[5];
  const float* Wk   = (const float*)d_in[6];
  const float* Wv   = (const float*)d_in[7];
  const float* ln1g = (const float*)d_in[8];
  const float* ln1b = (const float*)d_in[9];
  const float* W1   = (const float*)d_in[10];
  const float* b1   = (const float*)d_in[11];
  const float* W2   = (const float*)d_in[12];
  const float* b2   = (const float*)d_in[13];
  const float* ln2g = (const float*)d_in[14];
  const float* ln2b = (const float*)d_in[15];
  const float* Wp   = (const float*)d_in[16];
  const float* bp   = (const float*)d_in[17];
  float* out = (float*)d_out;

  const long long sQ = (long long)N_SEQ * E_DIM;   // per-batch activation elems
  const long long sS = (long long)N_SEQ * N_SEQ;   // per-batch score elems

  // ws: Hs(f32) dbuf(f32) + bf16 hi/lo for {Hs,q,k,vT,S} + wt hi/lo + Aemb
  auto need = [&](int G) -> size_t {
    return (size_t)G * sQ * 24 + (size_t)G * sS * 4
         + (size_t)E_DIM * E_DIM * 4 + (size_t)G * E_DIM * 4 + (size_t)65536;
  };
  int G = 16;
  while (G > 1 && need(G) > ws_size) G >>= 1;
  if (need(G) > ws_size || d_ws == nullptr) {
    fill_sentinel<<<dim3((out_size + 255) / 256), 256, 0, stream>>>(out, out_size, 1.0e7f);
    return;
  }

  char* ws = (char*)d_ws;
  size_t off = 0;
  auto alloc = [&](size_t bytes) -> void* {
    void* p = ws + off;
    off += (bytes + 255) & ~(size_t)255;
    return p;
  };
  float* Hs   = (float*)alloc((size_t)G * sQ * 4);
  float* dbuf = (float*)alloc((size_t)G * sQ * 4);
  u16* hsh = (u16*)alloc((size_t)G * sQ * 2);
  u16* hsl = (u16*)alloc((size_t)G * sQ * 2);
  u16* qh  = (u16*)alloc((size_t)G * sQ * 2);   // q hi, later MLP hidden hi
  u16* ql  = (u16*)alloc((size_t)G * sQ * 2);
  u16* kh  = (u16*)alloc((size_t)G * sQ * 2);
  u16* kl  = (u16*)alloc((size_t)G * sQ * 2);
  u16* vh  = (u16*)alloc((size_t)G * sQ * 2);   // vT [E][N] per batch
  u16* vl  = (u16*)alloc((size_t)G * sQ * 2);
  u16* sh  = (u16*)alloc((size_t)G * sS * 2);
  u16* sl  = (u16*)alloc((size_t)G * sS * 2);
  u16* wth = (u16*)alloc((size_t)E_DIM * E_DIM * 2);
  u16* wtl = (u16*)alloc((size_t)E_DIM * E_DIM * 2);
  float* Aemb = (float*)alloc((size_t)G * E_DIM * 4);

  const int tE = E_DIM / TN;            // 8 column tiles over E
  const int tS = N_SEQ / TN;            // 8 tiles over sequence
  const int triS = tS * (tS + 1) / 2;   // 36
  const dim3 gq((G * N_SEQ / TM) * tE, 1);   // folded-batch QKV/MLP grid
  const dim3 gsq(triS, G);                   // triangular S grid
  const dim3 gv(tE * tS, G);                 // vT / S@V grid (8x8 tiles)
  const dim3 gT(E_DIM / 32, E_DIM / 32);

  for (int g0 = 0; g0 < B_SZ; g0 += G) {
    emb_dot<<<dim3(E_DIM / 256, G), 256, 0, stream>>>(act + (long long)g0 * ACT_D, Wemb, Aemb);
    emb_fill<<<dim3(N_SEQ, G), 256, 0, stream>>>(Aemb, Wemb, bemb, wpe, Hs, hsh, hsl);

    for (int l = 0; l < L_NUM; l++) {
      const long long wof = (long long)l * E_DIM * E_DIM;
      const long long bof = (long long)l * E_DIM;

      // q = Hs @ Wq^T (batch folded into M) -> bf16 hi/lo
      transpose_split<<<gT, 256, 0, stream>>>(Wq + wof, wth, wtl, E_DIM, E_DIM);
      gemm_nt_mfma<0, 1><<<gq, 256, 0, stream>>>(hsh, hsl, wth, wtl,
          nullptr, qh, ql, nullptr, E_DIM, E_DIM, E_DIM, E_DIM, tE, 0, 0, 0);
      // k = Hs @ Wk^T -> bf16 hi/lo
      transpose_split<<<gT, 256, 0, stream>>>(Wk + wof, wth, wtl, E_DIM, E_DIM);
      gemm_nt_mfma<0, 1><<<gq, 256, 0, stream>>>(hsh, hsl, wth, wtl,
          nullptr, kh, kl, nullptr, E_DIM, E_DIM, E_DIM, E_DIM, tE, 0, 0, 0);

      // S = relu(q k^T) * causal/(row+1), lower-triangular tiles -> hi/lo
      gemm_nt_mfma<1, 3><<<gsq, 256, 0, stream>>>(qh, ql, kh, kl,
          nullptr, sh, sl, nullptr, E_DIM, E_DIM, E_DIM, N_SEQ, tS, sQ, sQ, sS);

      // vT[e][j] = sum_k WvT[e][k] * Hs[j][k] -> hi/lo (B = per-batch Hs)
      transpose_split<<<gT, 256, 0, stream>>>(Wv + wof, wth, wtl, E_DIM, E_DIM);
      gemm_nt_mfma<0, 1><<<gv, 256, 0, stream>>>(wth, wtl, hsh, hsl,
          nullptr, vh, vl, nullptr, E_DIM, E_DIM, E_DIM, N_SEQ, tS, 0, sQ, sQ);

      // attn delta = S @ v (K capped at diagonal) -> fp32 dbuf
      gemm_nt_mfma<2, 0><<<gv, 256, 0, stream>>>(sh, sl, vh, vl,
          dbuf, nullptr, nullptr, nullptr, N_SEQ, N_SEQ, N_SEQ, E_DIM, tE, sS, sQ, sQ);

      // Hs = LN1(Hs + delta); refresh Hs hi/lo
      resid_ln<<<dim3(G * N_SEQ), 256, 0, stream>>>(Hs, dbuf,
          ln1g + bof, ln1b + bof, hsh, hsl);

      // MLP: hidden = relu(Hs@W1^T + b1) -> hi/lo ; delta = hidden@W2^T + b2 -> fp32
      transpose_split<<<gT, 256, 0, stream>>>(W1 + wof, wth, wtl, E_DIM, E_DIM);
      gemm_nt_mfma<0, 2><<<gq, 256, 0, stream>>>(hsh, hsl, wth, wtl,
          nullptr, qh, ql, b1 + bof, E_DIM, E_DIM, E_DIM, E_DIM, tE, 0, 0, 0);
      transpose_split<<<gT, 256, 0, stream>>>(W2 + wof, wth, wtl, E_DIM, E_DIM);
      gemm_nt_mfma<0, 4><<<gq, 256, 0, stream>>>(qh, ql, wth, wtl,
          dbuf, nullptr, nullptr, b2 + bof, E_DIM, E_DIM, E_DIM, E_DIM, tE, 0, 0, 0);

      // Hs = LN2(Hs + delta); refresh Hs hi/lo
      resid_ln<<<dim3(G * N_SEQ), 256, 0, stream>>>(Hs, dbuf,
          ln2g + bof, ln2b + bof, hsh, hsl);
    }

    pred_k<<<dim3(N_SEQ / 2, G), 256, 0, stream>>>(Hs, Wp, bp,
        out + (long long)g0 * (N_SEQ / 2) * ADIM_);
  }
}

// Round 2
// 9510.386 us; speedup vs baseline: 1.2010x; 1.2010x over previous
//
#include <hip/hip_runtime.h>
#include <stdint.h>
#include <stddef.h>

// Problem constants (test=False shapes)
#define E_DIM 1024
#define B_SZ  16
#define N_SEQ 1024
#define L_NUM 12
#define ACT_D 640   // DIM*ACT_NUM
#define ADIM_ 10

typedef unsigned short u16;
typedef __attribute__((ext_vector_type(8))) short bf16x8;
typedef __attribute__((ext_vector_type(4))) float f32x4;

__device__ __forceinline__ u16 f2bf(float x) {
  union { float f; unsigned int u; } c; c.f = x;
  unsigned int r = c.u + 0x7fffu + ((c.u >> 16) & 1u);
  return (u16)(r >> 16);
}
__device__ __forceinline__ float bf2f(u16 h) {
  union { unsigned int u; float f; } c; c.u = ((unsigned int)h) << 16;
  return c.f;
}

struct us4 { u16 x, y, z, w; };

#define GLD16(gsrc, ldst) __builtin_amdgcn_global_load_lds( \
    (const __attribute__((address_space(1))) void*)(gsrc),  \
    (__attribute__((address_space(3))) void*)(ldst), 16, 0, 0)

// ---------------------------------------------------------------------------
// Error-compensated split-bf16 MFMA NT GEMM, 2-phase double-buffered.
//   C[M,N] = A[M,K] @ B[N,K]^T  =  Ah@Bh^T + Ah@Bl^T + Al@Bh^T   (fp32 acc)
// Tile 128x128, BK=32, 256 threads (2x2 waves of 64x64), 4x4 frags of
// mfma_f32_16x16x32_bf16. K-loop: stage(next buf) || compute(cur buf),
// single __syncthreads()/step (its vmcnt0+lgkmcnt0 drain IS the wanted wait).
// LDS: 2 bufs x 4 tiles(Ah,Al,Bh,Bl) x 8KB = 64KB.
// Bank-conflict fix: k-chunk XOR swizzle j^=(row>>1)&3 (16B granule),
// applied on the global SOURCE address (linear LDS dest, rule #21) and on
// the ds_read offset.
// blockIdx.z selects B/C set (fused Q+K). m204 bijective XCD swizzle on bid.
// MODE 0: full grid; MODE 1: lower-triangular tiles; MODE 2: K capped at
// (tm+1)*128 (causal S@V).
// EPI 0: Co=acc | 1: split->Ch/Cl | 2: split relu(acc+bias) | 3: split
// causal relu(acc)/(row+1) | 4: Co=acc+bias.
// ---------------------------------------------------------------------------
#define TM 128
#define TN 128
#define TK 32

template<int MODE, int EPI>
__global__ __launch_bounds__(256)
void gemm_nt_mfma(const u16* __restrict__ Ah, const u16* __restrict__ Al,
                  const u16* __restrict__ Bh0, const u16* __restrict__ Bl0,
                  const u16* __restrict__ Bh1, const u16* __restrict__ Bl1,
                  float* __restrict__ Co,
                  u16* __restrict__ Ch0, u16* __restrict__ Cl0,
                  u16* __restrict__ Ch1, u16* __restrict__ Cl1,
                  const float* __restrict__ bias0, const float* __restrict__ bias1,
                  int K, int lda, int ldb, int ldc, int tilesN,
                  long long sA, long long sB, long long sC)
{
  __shared__ u16 smem[2 * 4 * TM * TK];   // 64 KB

  const int tid = threadIdx.x;
  const int bat = blockIdx.y;

  const u16* Bh = Bh0; const u16* Bl = Bl0;
  u16* Ch = Ch0; u16* Cl = Cl0;
  const float* bias = bias0;
  if (blockIdx.z) { Bh = Bh1; Bl = Bl1; Ch = Ch1; Cl = Cl1; bias = bias1; }

  Ah += bat * sA; Al += bat * sA;
  Bh += bat * sB; Bl += bat * sB;

  // bijective XCD-aware block swizzle (m204)
  int bid;
  {
    const int nwg = gridDim.x;
    const int q = nwg >> 3, r = nwg & 7;
    const int xcd = blockIdx.x & 7, off = blockIdx.x >> 3;
    bid = ((xcd < r) ? xcd * (q + 1) : r * (q + 1) + (xcd - r) * q) + off;
  }

  int tm, tn;
  if (MODE == 1) {
    int t = bid, m = 0;
    while ((m + 1) * (m + 2) / 2 <= t) m++;
    tm = m; tn = t - m * (m + 1) / 2;
  } else {
    tm = bid / tilesN;
    tn = bid % tilesN;
  }
  int kend = K;
  if (MODE == 2) { int c = (tm + 1) * TM; kend = (c < K) ? c : K; }
  const int nk = kend / TK;

  // staging: 512 16B-chunks/tile, 2/thread. chunk c -> LDS u16 off c*8
  // (linear, lane-ordered). Source k-chunk pre-swizzled: j ^= (row>>1)&3.
  const int c0 = tid, c1 = tid + 256;
  const int r0 = c0 >> 2, r1 = c1 >> 2;
  const int p0 = ((c0 & 3) ^ ((r0 >> 1) & 3)) * 8;
  const int p1 = ((c1 & 3) ^ ((r1 >> 1) & 3)) * 8;
  const u16* gAh0 = Ah + (long long)(tm * TM + r0) * lda + p0;
  const u16* gAh1 = Ah + (long long)(tm * TM + r1) * lda + p1;
  const u16* gAl0 = Al + (long long)(tm * TM + r0) * lda + p0;
  const u16* gAl1 = Al + (long long)(tm * TM + r1) * lda + p1;
  const u16* gBh0 = Bh + (long long)(tn * TN + r0) * ldb + p0;
  const u16* gBh1 = Bh + (long long)(tn * TN + r1) * ldb + p1;
  const u16* gBl0 = Bl + (long long)(tn * TN + r0) * ldb + p0;
  const u16* gBl1 = Bl + (long long)(tn * TN + r1) * ldb + p1;
  const int o0 = c0 * 8, o1 = c1 * 8;

  auto stage = [&](int buf) {
    u16* base = smem + buf * 16384;
    GLD16(gAh0, base + o0);          GLD16(gAh1, base + o1);
    GLD16(gAl0, base + 4096 + o0);   GLD16(gAl1, base + 4096 + o1);
    GLD16(gBh0, base + 8192 + o0);   GLD16(gBh1, base + 8192 + o1);
    GLD16(gBl0, base + 12288 + o0);  GLD16(gBl1, base + 12288 + o1);
    gAh0 += TK; gAh1 += TK; gAl0 += TK; gAl1 += TK;
    gBh0 += TK; gBh1 += TK; gBl0 += TK; gBl1 += TK;
  };

  // fragment read offsets (u16 units), with matching XOR swizzle
  const int lane = tid & 63;
  const int w = tid >> 6, wr = w >> 1, wc = w & 1;
  const int fr = lane & 15;
  const int kq = (lane >> 4) * 8;
  const int sa = ((fr >> 1) & 3) << 3;            // XOR on idx bits 3..4
  const int aoff = ((wr * 64 + fr) * TK + kq) ^ sa;
  const int boff = ((wc * 64 + fr) * TK + kq) ^ sa;

  f32x4 acc[4][4];
  #pragma unroll
  for (int m = 0; m < 4; m++)
    #pragma unroll
    for (int n = 0; n < 4; n++) acc[m][n] = (f32x4){0.f, 0.f, 0.f, 0.f};

  stage(0);
  __syncthreads();   // drains vmcnt(0): buf0 ready

  for (int t = 0; t < nk; t++) {
    if (t + 1 < nk) stage((t + 1) & 1);   // prefetch next tile (other buf)
    const u16* sb = smem + (t & 1) * 16384;

    bf16x8 ah[4], al[4], bh[4], bl[4];
    #pragma unroll
    for (int m = 0; m < 4; m++) ah[m] = *(const bf16x8*)(sb + aoff + m * 512);
    #pragma unroll
    for (int n = 0; n < 4; n++) bh[n] = *(const bf16x8*)(sb + 8192 + boff + n * 512);
    #pragma unroll
    for (int m = 0; m < 4; m++)
      #pragma unroll
      for (int n = 0; n < 4; n++)
        acc[m][n] = __builtin_amdgcn_mfma_f32_16x16x32_bf16(ah[m], bh[n], acc[m][n], 0, 0, 0);
    #pragma unroll
    for (int n = 0; n < 4; n++) bl[n] = *(const bf16x8*)(sb + 12288 + boff + n * 512);
    #pragma unroll
    for (int m = 0; m < 4; m++)
      #pragma unroll
      for (int n = 0; n < 4; n++)
        acc[m][n] = __builtin_amdgcn_mfma_f32_16x16x32_bf16(ah[m], bl[n], acc[m][n], 0, 0, 0);
    #pragma unroll
    for (int m = 0; m < 4; m++) al[m] = *(const bf16x8*)(sb + 4096 + aoff + m * 512);
    #pragma unroll
    for (int m = 0; m < 4; m++)
      #pragma unroll
      for (int n = 0; n < 4; n++)
        acc[m][n] = __builtin_amdgcn_mfma_f32_16x16x32_bf16(al[m], bh[n], acc[m][n], 0, 0, 0);

    __syncthreads();   // waits prefetch (vmcnt0) + guards buf reuse
  }

  // epilogue: C/D layout col = lane&15, row = (lane>>4)*4 + reg  [m89/m91]
  if (Co) Co += bat * sC;
  if (Ch) { Ch += bat * sC; Cl += bat * sC; }
  #pragma unroll
  for (int m = 0; m < 4; m++) {
    #pragma unroll
    for (int r = 0; r < 4; r++) {
      const long long row = (long long)tm * TM + wr * 64 + m * 16 + (lane >> 4) * 4 + r;
      #pragma unroll
      for (int n = 0; n < 4; n++) {
        const long long col = (long long)tn * TN + wc * 64 + n * 16 + (lane & 15);
        float v = acc[m][n][r];
        if (EPI == 2) { v += bias[col]; v = v > 0.f ? v : 0.f; }
        if (EPI == 4) { v += bias[col]; }
        if (EPI == 3) {
          v = v > 0.f ? v : 0.f;
          v = (col <= row) ? v / (float)(row + 1) : 0.f;
        }
        const long long idx = row * (long long)ldc + col;
        if (EPI == 0 || EPI == 4) {
          Co[idx] = v;
        } else {
          u16 h = f2bf(v);
          Ch[idx] = h;
          Cl[idx] = f2bf(v - bf2f(h));
        }
      }
    }
  }
}

// ---------------------------------------------------------------------------
// Fused weight transposes: up to 3 E x E fp32 -> bf16 hi/lo (dst = src^T)
// ---------------------------------------------------------------------------
struct TP3 {
  const float* s0; const float* s1; const float* s2;
  u16* h0; u16* l0; u16* h1; u16* l1; u16* h2; u16* l2;
};

__global__ __launch_bounds__(256)
void transpose_split3(TP3 p)
{
  __shared__ float tile[32][33];
  const float* src; u16* dh; u16* dl;
  if (blockIdx.z == 0)      { src = p.s0; dh = p.h0; dl = p.l0; }
  else if (blockIdx.z == 1) { src = p.s1; dh = p.h1; dl = p.l1; }
  else                      { src = p.s2; dh = p.h2; dl = p.l2; }
  const int c0 = blockIdx.x * 32, r0 = blockIdx.y * 32;
  const int tx = threadIdx.x & 31, ty = threadIdx.x >> 5;  // 32x8
  #pragma unroll
  for (int i = ty; i < 32; i += 8)
    tile[i][tx] = src[(long long)(r0 + i) * E_DIM + c0 + tx];
  __syncthreads();
  #pragma unroll
  for (int i = ty; i < 32; i += 8) {
    const float v = tile[tx][i];
    const u16 h = f2bf(v);
    const long long idx = (long long)(c0 + i) * E_DIM + r0 + tx;
    dh[idx] = h;
    dl[idx] = f2bf(v - bf2f(h));
  }
}

// ---------------------------------------------------------------------------
// Residual add + LayerNorm on the bf16-pair residual stream:
//   x = (hh+hl) + delta;  (hh,hl) = split(LN(x)*g + b)
// ---------------------------------------------------------------------------
__global__ __launch_bounds__(256)
void resid_ln(u16* __restrict__ hh, u16* __restrict__ hl,
              const float* __restrict__ delta,
              const float* __restrict__ g, const float* __restrict__ bta)
{
  __shared__ float red[8];
  const long long row = blockIdx.x;
  u16* hp = hh + row * E_DIM;
  u16* lp = hl + row * E_DIM;
  const float* dp = delta + row * E_DIM;
  const int tid = threadIdx.x;
  const int e = tid * 4;

  us4 hv = *(const us4*)(hp + e);
  us4 lv = *(const us4*)(lp + e);
  float4 d = *(const float4*)(dp + e);
  float x0 = bf2f(hv.x) + bf2f(lv.x) + d.x;
  float x1 = bf2f(hv.y) + bf2f(lv.y) + d.y;
  float x2 = bf2f(hv.z) + bf2f(lv.z) + d.z;
  float x3 = bf2f(hv.w) + bf2f(lv.w) + d.w;
  float s = x0 + x1 + x2 + x3;
  float q = x0 * x0 + x1 * x1 + x2 * x2 + x3 * x3;
  #pragma unroll
  for (int o = 32; o > 0; o >>= 1) { s += __shfl_down(s, o); q += __shfl_down(q, o); }
  const int lane = tid & 63, wv = tid >> 6;
  if (lane == 0) { red[wv] = s; red[wv + 4] = q; }
  __syncthreads();
  const float st = red[0] + red[1] + red[2] + red[3];
  const float qt = red[4] + red[5] + red[6] + red[7];
  const float mu = st * (1.0f / E_DIM);
  const float var = qt * (1.0f / E_DIM) - mu * mu;
  const float rstd = rsqrtf(var + 1e-5f);

  float4 gg = *(const float4*)(g + e);
  float4 bb = *(const float4*)(bta + e);
  float y0 = (x0 - mu) * rstd * gg.x + bb.x;
  float y1 = (x1 - mu) * rstd * gg.y + bb.y;
  float y2 = (x2 - mu) * rstd * gg.z + bb.z;
  float y3 = (x3 - mu) * rstd * gg.w + bb.w;

  us4 ho, lo;
  ho.x = f2bf(y0); lo.x = f2bf(y0 - bf2f(ho.x));
  ho.y = f2bf(y1); lo.y = f2bf(y1 - bf2f(ho.y));
  ho.z = f2bf(y2); lo.z = f2bf(y2 - bf2f(ho.z));
  ho.w = f2bf(y3); lo.w = f2bf(y3 - bf2f(ho.w));
  *(us4*)(hp + e) = ho;
  *(us4*)(lp + e) = lo;
}

// ---------------------------------------------------------------------------
// Embedding: A_emb[b,e] = act[b,:640] @ W_emb[:640, e]
// ---------------------------------------------------------------------------
__global__ __launch_bounds__(256)
void emb_dot(const float* __restrict__ act, const float* __restrict__ Wemb,
             float* __restrict__ Aemb)
{
  const int e = blockIdx.x * 256 + threadIdx.x;
  const int b = blockIdx.y;
  const float* ab = act + b * ACT_D;
  float s = 0.f;
  for (int d = 0; d < ACT_D; d++)
    s = fmaf(ab[d], Wemb[(long long)d * E_DIM + e], s);
  Aemb[b * E_DIM + e] = s;
}

// Hs[b,i,:] = (i even ? A_emb[b] : 0) + b_emb + W_emb[651] + (i+1)*W_emb[652] + wpe[i]
__global__ __launch_bounds__(256)
void emb_fill(const float* __restrict__ Aemb, const float* __restrict__ Wemb,
              const float* __restrict__ bemb, const float* __restrict__ wpe,
              u16* __restrict__ oh, u16* __restrict__ ol)
{
  const int i = blockIdx.x, b = blockIdx.y;
  const int e = threadIdx.x * 4;
  float4 a;
  if ((i & 1) == 0) a = *(const float4*)(Aemb + b * E_DIM + e);
  else { a.x = 0.f; a.y = 0.f; a.z = 0.f; a.w = 0.f; }
  float4 be = *(const float4*)(bemb + e);
  float4 w1 = *(const float4*)(Wemb + 651LL * E_DIM + e);
  float4 w2 = *(const float4*)(Wemb + 652LL * E_DIM + e);
  float4 pw = *(const float4*)(wpe + (long long)i * E_DIM + e);
  const float pos = (float)(i + 1);
  float y0 = a.x + be.x + w1.x + pos * w2.x + pw.x;
  float y1 = a.y + be.y + w1.y + pos * w2.y + pw.y;
  float y2 = a.z + be.z + w1.z + pos * w2.z + pw.z;
  float y3 = a.w + be.w + w1.w + pos * w2.w + pw.w;
  const long long row = (long long)b * N_SEQ + i;

  us4 ho, lo;
  ho.x = f2bf(y0); lo.x = f2bf(y0 - bf2f(ho.x));
  ho.y = f2bf(y1); lo.y = f2bf(y1 - bf2f(ho.y));
  ho.z = f2bf(y2); lo.z = f2bf(y2 - bf2f(ho.z));
  ho.w = f2bf(y3); lo.w = f2bf(y3 - bf2f(ho.w));
  *(us4*)(oh + row * E_DIM + e) = ho;
  *(us4*)(ol + row * E_DIM + e) = lo;
}

// ---------------------------------------------------------------------------
// Final head: out[b,h,:] = (hh+hl)[b,2h,:] @ W_pred + b_pred
// ---------------------------------------------------------------------------
__global__ __launch_bounds__(256)
void pred_k(const u16* __restrict__ hh, const u16* __restrict__ hl,
            const float* __restrict__ Wp, const float* __restrict__ bp,
            float* __restrict__ out)
{
  __shared__ float part[4][ADIM_];
  const int h = blockIdx.x, b = blockIdx.y;
  const long long row = (long long)b * N_SEQ + 2 * h;
  const u16* xh = hh + row * E_DIM;
  const u16* xl = hl + row * E_DIM;
  float acc[ADIM_];
  #pragma unroll
  for (int a = 0; a < ADIM_; a++) acc[a] = 0.f;
  for (int e = threadIdx.x; e < E_DIM; e += 256) {
    const float xv = bf2f(xh[e]) + bf2f(xl[e]);
    const float* wq = Wp + e * ADIM_;
    #pragma unroll
    for (int a = 0; a < ADIM_; a++) acc[a] = fmaf(xv, wq[a], acc[a]);
  }
  const int lane = threadIdx.x & 63, wv = threadIdx.x >> 6;
  #pragma unroll
  for (int a = 0; a < ADIM_; a++)
    #pragma unroll
    for (int o = 32; o > 0; o >>= 1) acc[a] += __shfl_down(acc[a], o);
  if (lane == 0)
    #pragma unroll
    for (int a = 0; a < ADIM_; a++) part[wv][a] = acc[a];
  __syncthreads();
  if (threadIdx.x < ADIM_) {
    const int a = threadIdx.x;
    out[((long long)b * (N_SEQ / 2) + h) * ADIM_ + a] =
        part[0][a] + part[1][a] + part[2][a] + part[3][a] + bp[a];
  }
}

// Diagnostic sentinel: unambiguous "workspace too small" signature
__global__ __launch_bounds__(256)
void fill_sentinel(float* p, int n, float v)
{
  int i = blockIdx.x * 256 + threadIdx.x;
  if (i < n) p[i] = v;
}

// ---------------------------------------------------------------------------
extern "C" void kernel_launch(void* const* d_in, const int* in_sizes, int n_in,
                              void* d_out, int out_size, void* d_ws, size_t ws_size,
                              hipStream_t stream)
{
  const float* act  = (const float*)d_in[0];
  // d_in[1] context_rewards: numerically unused by the reference
  const float* wpe  = (const float*)d_in[2];
  const float* Wemb = (const float*)d_in[3];
  const float* bemb = (const float*)d_in[4];
  const float* Wq   = (const float*)d_in[5];
  const float* Wk   = (const float*)d_in[6];
  const float* Wv   = (const float*)d_in[7];
  const float* ln1g = (const float*)d_in[8];
  const float* ln1b = (const float*)d_in[9];
  const float* W1   = (const float*)d_in[10];
  const float* b1   = (const float*)d_in[11];
  const float* W2   = (const float*)d_in[12];
  const float* b2   = (const float*)d_in[13];
  const float* ln2g = (const float*)d_in[14];
  const float* ln2b = (const float*)d_in[15];
  const float* Wp   = (const float*)d_in[16];
  const float* bp   = (const float*)d_in[17];
  float* out = (float*)d_out;

  const long long sQ = (long long)N_SEQ * E_DIM;   // per-batch elems (= N^2 too)
  const long long sE = (long long)E_DIM * E_DIM;

  // ws: per-batch 16B/elem: hs pair(4) + q pair(4) + kreg(4: k pair | dbuf f32)
  //     + s pair(4); shared: 3 wt pairs (12.6MB) + Aemb
  auto need = [&](int G) -> size_t {
    return (size_t)G * sQ * 16 + (size_t)sE * 12
         + (size_t)G * E_DIM * 4 + (size_t)(1 << 20);
  };
  int G = 16;
  while (G > 1 && need(G) > ws_size) G >>= 1;
  if (need(G) > ws_size || d_ws == nullptr) {
    fill_sentinel<<<dim3((out_size + 255) / 256), 256, 0, stream>>>(out, out_size, 1.0e7f);
    return;
  }

  char* ws = (char*)d_ws;
  size_t off = 0;
  auto alloc = [&](size_t bytes) -> void* {
    void* p = ws + off;
    off += (bytes + 255) & ~(size_t)255;
    return p;
  };
  u16* hsh = (u16*)alloc((size_t)G * sQ * 2);
  u16* hsl = (u16*)alloc((size_t)G * sQ * 2);
  u16* qh  = (u16*)alloc((size_t)G * sQ * 2);   // q -> vT -> MLP hidden
  u16* ql  = (u16*)alloc((size_t)G * sQ * 2);
  char* kreg = (char*)alloc((size_t)G * sQ * 4);  // k pair, later dbuf f32
  u16* kh = (u16*)kreg;
  u16* kl = kh + (size_t)G * sQ;
  float* dbuf = (float*)kreg;
  u16* sh_ = (u16*)alloc((size_t)G * sQ * 2);
  u16* sl_ = (u16*)alloc((size_t)G * sQ * 2);
  u16* wAh = (u16*)alloc((size_t)sE * 2);
  u16* wAl = (u16*)alloc((size_t)sE * 2);
  u16* wBh = (u16*)alloc((size_t)sE * 2);
  u16* wBl = (u16*)alloc((size_t)sE * 2);
  u16* wCh = (u16*)alloc((size_t)sE * 2);
  u16* wCl = (u16*)alloc((size_t)sE * 2);
  float* Aemb = (float*)alloc((size_t)G * E_DIM * 4);

  const int tE = E_DIM / TN;            // 8
  const int tS = N_SEQ / TN;            // 8
  const int triS = tS * (tS + 1) / 2;   // 36
  const dim3 gqk((G * N_SEQ / TM) * tE, 1, 2);   // fused Q+K (batch in M)
  const dim3 gm ((G * N_SEQ / TM) * tE, 1, 1);   // MLP GEMMs
  const dim3 gsq(triS, G, 1);                    // triangular S
  const dim3 gv (tE * tS, G, 1);                 // vT / S@V

  for (int g0 = 0; g0 < B_SZ; g0 += G) {
    emb_dot<<<dim3(E_DIM / 256, G), 256, 0, stream>>>(act + (long long)g0 * ACT_D, Wemb, Aemb);
    emb_fill<<<dim3(N_SEQ, G), 256, 0, stream>>>(Aemb, Wemb, bemb, wpe, hsh, hsl);

    for (int l = 0; l < L_NUM; l++) {
      const long long wof = (long long)l * sE;
      const long long bof = (long long)l * E_DIM;

      // Wq,Wk -> wA,wB (hi/lo, transposed)
      TP3 t2 = {Wq + wof, Wk + wof, Wq + wof, wAh, wAl, wBh, wBl, wAh, wAl};
      transpose_split3<<<dim3(32, 32, 2), 256, 0, stream>>>(t2);
      // fused q|k = Hs @ {Wq,Wk}^T -> pairs
      gemm_nt_mfma<0, 1><<<gqk, 256, 0, stream>>>(hsh, hsl, wAh, wAl, wBh, wBl,
          nullptr, qh, ql, kh, kl, nullptr, nullptr,
          E_DIM, E_DIM, E_DIM, E_DIM, tE, 0, 0, 0);

      // Wv,W1,W2 -> wA,wB,wC (runs after QK; stream-serial)
      TP3 t3 = {Wv + wof, W1 + wof, W2 + wof, wAh, wAl, wBh, wBl, wCh, wCl};
      transpose_split3<<<dim3(32, 32, 3), 256, 0, stream>>>(t3);

      // S = relu(q k^T) * causal/(row+1), lower-triangular tiles -> pair
      gemm_nt_mfma<1, 3><<<gsq, 256, 0, stream>>>(qh, ql, kh, kl, kh, kl,
          nullptr, sh_, sl_, sh_, sl_, nullptr, nullptr,
          E_DIM, E_DIM, E_DIM, N_SEQ, tS, sQ, sQ, sQ);

      // vT[e][j] = WvT[e][:] . Hs[j][:]  -> q pair (q dead after S)
      gemm_nt_mfma<0, 1><<<gv, 256, 0, stream>>>(wAh, wAl, hsh, hsl, hsh, hsl,
          nullptr, qh, ql, qh, ql, nullptr, nullptr,
          E_DIM, E_DIM, E_DIM, N_SEQ, tS, 0, sQ, sQ);

      // attn delta = S @ v (K capped at diagonal) -> dbuf (over dead k)
      gemm_nt_mfma<2, 0><<<gv, 256, 0, stream>>>(sh_, sl_, qh, ql, qh, ql,
          dbuf, nullptr, nullptr, nullptr, nullptr, nullptr, nullptr,
          N_SEQ, N_SEQ, N_SEQ, E_DIM, tE, sQ, sQ, sQ);

      // Hs = LN1(Hs + delta)
      resid_ln<<<dim3(G * N_SEQ), 256, 0, stream>>>(hsh, hsl, dbuf,
          ln1g + bof, ln1b + bof);

      // MLP: hidden = relu(Hs@W1^T + b1) -> q pair
      gemm_nt_mfma<0, 2><<<gm, 256, 0, stream>>>(hsh, hsl, wBh, wBl, wBh, wBl,
          nullptr, qh, ql, qh, ql, b1 + bof, b1 + bof,
          E_DIM, E_DIM, E_DIM, E_DIM, tE, 0, 0, 0);
      // delta = hidden@W2^T + b2 -> dbuf
      gemm_nt_mfma<0, 4><<<gm, 256, 0, stream>>>(qh, ql, wCh, wCl, wCh, wCl,
          dbuf, nullptr, nullptr, nullptr, nullptr, b2 + bof, b2 + bof,
          E_DIM, E_DIM, E_DIM, E_DIM, tE, 0, 0, 0);

      // Hs = LN2(Hs + delta)
      resid_ln<<<dim3(G * N_SEQ), 256, 0, stream>>>(hsh, hsl, dbuf,
          ln2g + bof, ln2b + bof);
    }

    pred_k<<<dim3(N_SEQ / 2, G), 256, 0, stream>>>(hsh, hsl, Wp, bp,
        out + (long long)g0 * (N_SEQ / 2) * ADIM_);
  }
}

// Round 3
// 9223.754 us; speedup vs baseline: 1.2383x; 1.0311x over previous
//
#include <hip/hip_runtime.h>
#include <stdint.h>
#include <stddef.h>

// Problem constants (test=False shapes)
#define E_DIM 1024
#define B_SZ  16
#define N_SEQ 1024
#define L_NUM 12
#define ACT_D 640   // DIM*ACT_NUM
#define ADIM_ 10

typedef unsigned short u16;
typedef __attribute__((ext_vector_type(8))) short bf16x8;
typedef __attribute__((ext_vector_type(4))) float f32x4;

__device__ __forceinline__ u16 f2bf(float x) {
  union { float f; unsigned int u; } c; c.f = x;
  unsigned int r = c.u + 0x7fffu + ((c.u >> 16) & 1u);
  return (u16)(r >> 16);
}
__device__ __forceinline__ float bf2f(u16 h) {
  union { unsigned int u; float f; } c; c.u = ((unsigned int)h) << 16;
  return c.f;
}

struct us4 { u16 x, y, z, w; };

#define GLD16(gsrc, ldst) __builtin_amdgcn_global_load_lds( \
    (const __attribute__((address_space(1))) void*)(gsrc),  \
    (__attribute__((address_space(3))) void*)(ldst), 16, 0, 0)

// ---------------------------------------------------------------------------
// Error-compensated split-bf16 MFMA NT GEMM, deep-pipelined (T3+T4 adapted).
//   C[M,N] = A[M,K] @ B[N,K]^T  =  Ah@Bh^T + Ah@Bl^T + Al@Bh^T   (fp32 acc)
// Tile 256x128, BK=32, 512 threads = 8 waves (2x4, each owns 128x32 out),
// per wave 8x2 frags of mfma_f32_16x16x32_bf16 x 3 passes = 48 MFMA/K-step.
// Pipeline: 3 LDS bufs x 48KB = 144KB. Per step: issue stage(t+2) ->
// compute(t) -> s_waitcnt vmcnt(6) [stage(t+1) landed; t+2 STAYS in flight,
// never drained to 0 in-loop] -> raw s_barrier. Each thread issues exactly
// 6 global_load_lds(16B) per stage (A:2+2, B:1+1) so vmcnt counts are exact.
// Bank-conflict-free via k-chunk XOR swizzle ((row>>1)&3, 16B granule) on
// BOTH the global source address and the ds_read offset (linear LDS dest).
// m204 bijective XCD-chunked bid swizzle, tm-major (A-panel L2 locality).
// MODE 0: full grid; MODE 1: causal-lower tiles (256-row x 128-col);
// MODE 2: K capped at (tm+1)*256 (causal S@V).
// EPI 0: Co=acc | 1: split->Ch/Cl | 2: split relu(acc+bias) | 3: split
// causal relu(acc)/(row+1) | 4: Co=acc+bias.
// M multiple of 256; N multiple of 128; K multiple of 32; K/32 >= 2.
// ---------------------------------------------------------------------------
#define BM 256
#define BN 128
#define BK 32
#define LDS_A 8192    // u16 per A operand tile (256*32)
#define LDS_B 4096    // u16 per B operand tile (128*32)
#define BUFU 24576    // u16 per buf (2*LDS_A + 2*LDS_B)

template<int MODE, int EPI>
__global__ __launch_bounds__(512)
void gemm_nt_mfma(const u16* __restrict__ Ah, const u16* __restrict__ Al,
                  const u16* __restrict__ Bh0, const u16* __restrict__ Bl0,
                  const u16* __restrict__ Bh1, const u16* __restrict__ Bl1,
                  float* __restrict__ Co,
                  u16* __restrict__ Ch0, u16* __restrict__ Cl0,
                  u16* __restrict__ Ch1, u16* __restrict__ Cl1,
                  const float* __restrict__ bias0, const float* __restrict__ bias1,
                  int K, int lda, int ldb, int ldc, int tilesN,
                  long long sA, long long sB, long long sC)
{
  __shared__ u16 smem[3 * BUFU];   // 144 KB

  const int tid = threadIdx.x;
  const int bat = blockIdx.y;

  const u16* Bh = Bh0; const u16* Bl = Bl0;
  u16* Ch = Ch0; u16* Cl = Cl0;
  const float* bias = bias0;
  if (blockIdx.z) { Bh = Bh1; Bl = Bl1; Ch = Ch1; Cl = Cl1; bias = bias1; }

  Ah += bat * sA; Al += bat * sA;
  Bh += bat * sB; Bl += bat * sB;

  // bijective XCD-aware block swizzle (m204); tm-major ordering downstream
  int bid;
  {
    const int nwg = gridDim.x;
    const int q = nwg >> 3, r = nwg & 7;
    const int xcd = blockIdx.x & 7, off = blockIdx.x >> 3;
    bid = ((xcd < r) ? xcd * (q + 1) : r * (q + 1) + (xcd - r) * q) + off;
  }

  int tm, tn;
  if (MODE == 1) {
    // causal tiles: tn*128 <= tm*256+255  ->  tn <= 2*tm+1; start(m)=m*(m+1)
    int t = bid, m = 0;
    while ((m + 1) * (m + 2) <= t) m++;
    tm = m; tn = t - m * (m + 1);
  } else {
    tm = bid / tilesN;
    tn = bid % tilesN;
  }
  int kend = K;
  if (MODE == 2) { int c = (tm + 1) * BM; kend = (c < K) ? c : K; }
  const int nk = kend / BK;

  // ---- staging map: per thread per stage: A-ops 2+2 chunks, B-ops 1+1 ----
  // A chunk c in 0..1023: row=c>>2, kchunk=c&3 (XOR-swizzled vs row)
  // B chunk c in 0..511:  row=c>>2, same swizzle
  const int ca0 = tid, ca1 = tid + 512, cb0 = tid;
  const int ra0 = ca0 >> 2, ra1 = ca1 >> 2, rb0 = cb0 >> 2;
  const int pa0 = ((ca0 & 3) ^ ((ra0 >> 1) & 3)) * 8;
  const int pa1 = ((ca1 & 3) ^ ((ra1 >> 1) & 3)) * 8;
  const int pb0 = ((cb0 & 3) ^ ((rb0 >> 1) & 3)) * 8;
  const u16* gAh0 = Ah + (long long)(tm * BM + ra0) * lda + pa0;
  const u16* gAh1 = Ah + (long long)(tm * BM + ra1) * lda + pa1;
  const u16* gAl0 = Al + (long long)(tm * BM + ra0) * lda + pa0;
  const u16* gAl1 = Al + (long long)(tm * BM + ra1) * lda + pa1;
  const u16* gBh0 = Bh + (long long)(tn * BN + rb0) * ldb + pb0;
  const u16* gBl0 = Bl + (long long)(tn * BN + rb0) * ldb + pb0;
  const int oa0 = ca0 * 8, oa1 = ca1 * 8, ob0 = cb0 * 8;

  int issued = 0;
  auto stage = [&]() {
    u16* base = smem + (issued % 3) * BUFU;
    GLD16(gAh0, base + oa0);
    GLD16(gAh1, base + oa1);
    GLD16(gAl0, base + LDS_A + oa0);
    GLD16(gAl1, base + LDS_A + oa1);
    GLD16(gBh0, base + 2 * LDS_A + ob0);
    GLD16(gBl0, base + 2 * LDS_A + LDS_B + ob0);
    gAh0 += BK; gAh1 += BK; gAl0 += BK; gAl1 += BK;
    gBh0 += BK; gBl0 += BK;
    issued++;
  };

  // ---- fragment read offsets (u16 units), matching XOR swizzle ----
  const int lane = tid & 63;
  const int w = tid >> 6, wr = w >> 2, wc = w & 3;   // 2x4 waves, 128x32 each
  const int fr = lane & 15;
  const int kq = (lane >> 4) * 8;
  const int sa = ((fr >> 1) & 3) << 3;               // XOR on u16-idx bits 3..4
  const int aoff = ((wr * 128 + fr) * BK + kq) ^ sa; // + m*16*BK per frag
  const int boff = ((wc * 32 + fr) * BK + kq) ^ sa;  // + n*16*BK per frag

  f32x4 acc[8][2];
  #pragma unroll
  for (int m = 0; m < 8; m++)
    #pragma unroll
    for (int n = 0; n < 2; n++) acc[m][n] = (f32x4){0.f, 0.f, 0.f, 0.f};

  // prologue: two stages in flight; wait for the first only
  stage(); stage();
  asm volatile("s_waitcnt vmcnt(6)" ::: "memory");
  __builtin_amdgcn_s_barrier();

  for (int t = 0; t < nk; t++) {
    if (issued < nk) stage();          // targets buf (t+2)%3, freed by barrier t-1
    const u16* sb = smem + (t % 3) * BUFU;

    bf16x8 ah[8], al[8], bh[2], bl[2];
    #pragma unroll
    for (int m = 0; m < 8; m++) ah[m] = *(const bf16x8*)(sb + aoff + m * (16 * BK));
    #pragma unroll
    for (int n = 0; n < 2; n++) bh[n] = *(const bf16x8*)(sb + 2 * LDS_A + boff + n * (16 * BK));
    __builtin_amdgcn_s_setprio(1);
    #pragma unroll
    for (int m = 0; m < 8; m++)
      #pragma unroll
      for (int n = 0; n < 2; n++)
        acc[m][n] = __builtin_amdgcn_mfma_f32_16x16x32_bf16(ah[m], bh[n], acc[m][n], 0, 0, 0);
    __builtin_amdgcn_s_setprio(0);
    #pragma unroll
    for (int n = 0; n < 2; n++) bl[n] = *(const bf16x8*)(sb + 2 * LDS_A + LDS_B + boff + n * (16 * BK));
    __builtin_amdgcn_s_setprio(1);
    #pragma unroll
    for (int m = 0; m < 8; m++)
      #pragma unroll
      for (int n = 0; n < 2; n++)
        acc[m][n] = __builtin_amdgcn_mfma_f32_16x16x32_bf16(ah[m], bl[n], acc[m][n], 0, 0, 0);
    __builtin_amdgcn_s_setprio(0);
    #pragma unroll
    for (int m = 0; m < 8; m++) al[m] = *(const bf16x8*)(sb + LDS_A + aoff + m * (16 * BK));
    __builtin_amdgcn_s_setprio(1);
    #pragma unroll
    for (int m = 0; m < 8; m++)
      #pragma unroll
      for (int n = 0; n < 2; n++)
        acc[m][n] = __builtin_amdgcn_mfma_f32_16x16x32_bf16(al[m], bh[n], acc[m][n], 0, 0, 0);
    __builtin_amdgcn_s_setprio(0);

    if (t + 1 < nk) {
      // stage(t+1) must have landed; stage(t+2) (if issued) stays in flight
      if (issued > t + 2) asm volatile("s_waitcnt vmcnt(6)" ::: "memory");
      else                asm volatile("s_waitcnt vmcnt(0)" ::: "memory");
      __builtin_amdgcn_s_barrier();
    }
  }

  // epilogue: C/D layout col = lane&15, row = (lane>>4)*4 + reg  [m89/m91]
  if (Co) Co += bat * sC;
  if (Ch) { Ch += bat * sC; Cl += bat * sC; }
  #pragma unroll
  for (int m = 0; m < 8; m++) {
    #pragma unroll
    for (int r = 0; r < 4; r++) {
      const long long row = (long long)tm * BM + wr * 128 + m * 16 + (lane >> 4) * 4 + r;
      #pragma unroll
      for (int n = 0; n < 2; n++) {
        const long long col = (long long)tn * BN + wc * 32 + n * 16 + (lane & 15);
        float v = acc[m][n][r];
        if (EPI == 2) { v += bias[col]; v = v > 0.f ? v : 0.f; }
        if (EPI == 4) { v += bias[col]; }
        if (EPI == 3) {
          v = v > 0.f ? v : 0.f;
          v = (col <= row) ? v / (float)(row + 1) : 0.f;
        }
        const long long idx = row * (long long)ldc + col;
        if (EPI == 0 || EPI == 4) {
          Co[idx] = v;
        } else {
          u16 h = f2bf(v);
          Ch[idx] = h;
          Cl[idx] = f2bf(v - bf2f(h));
        }
      }
    }
  }
}

// ---------------------------------------------------------------------------
// Fused weight transposes: up to 3 E x E fp32 -> bf16 hi/lo (dst = src^T)
// ---------------------------------------------------------------------------
struct TP3 {
  const float* s0; const float* s1; const float* s2;
  u16* h0; u16* l0; u16* h1; u16* l1; u16* h2; u16* l2;
};

__global__ __launch_bounds__(256)
void transpose_split3(TP3 p)
{
  __shared__ float tile[32][33];
  const float* src; u16* dh; u16* dl;
  if (blockIdx.z == 0)      { src = p.s0; dh = p.h0; dl = p.l0; }
  else if (blockIdx.z == 1) { src = p.s1; dh = p.h1; dl = p.l1; }
  else                      { src = p.s2; dh = p.h2; dl = p.l2; }
  const int c0 = blockIdx.x * 32, r0 = blockIdx.y * 32;
  const int tx = threadIdx.x & 31, ty = threadIdx.x >> 5;  // 32x8
  #pragma unroll
  for (int i = ty; i < 32; i += 8)
    tile[i][tx] = src[(long long)(r0 + i) * E_DIM + c0 + tx];
  __syncthreads();
  #pragma unroll
  for (int i = ty; i < 32; i += 8) {
    const float v = tile[tx][i];
    const u16 h = f2bf(v);
    const long long idx = (long long)(c0 + i) * E_DIM + r0 + tx;
    dh[idx] = h;
    dl[idx] = f2bf(v - bf2f(h));
  }
}

// ---------------------------------------------------------------------------
// Residual add + LayerNorm on the bf16-pair residual stream:
//   x = (hh+hl) + delta;  (hh,hl) = split(LN(x)*g + b)
// ---------------------------------------------------------------------------
__global__ __launch_bounds__(256)
void resid_ln(u16* __restrict__ hh, u16* __restrict__ hl,
              const float* __restrict__ delta,
              const float* __restrict__ g, const float* __restrict__ bta)
{
  __shared__ float red[8];
  const long long row = blockIdx.x;
  u16* hp = hh + row * E_DIM;
  u16* lp = hl + row * E_DIM;
  const float* dp = delta + row * E_DIM;
  const int tid = threadIdx.x;
  const int e = tid * 4;

  us4 hv = *(const us4*)(hp + e);
  us4 lv = *(const us4*)(lp + e);
  float4 d = *(const float4*)(dp + e);
  float x0 = bf2f(hv.x) + bf2f(lv.x) + d.x;
  float x1 = bf2f(hv.y) + bf2f(lv.y) + d.y;
  float x2 = bf2f(hv.z) + bf2f(lv.z) + d.z;
  float x3 = bf2f(hv.w) + bf2f(lv.w) + d.w;
  float s = x0 + x1 + x2 + x3;
  float q = x0 * x0 + x1 * x1 + x2 * x2 + x3 * x3;
  #pragma unroll
  for (int o = 32; o > 0; o >>= 1) { s += __shfl_down(s, o); q += __shfl_down(q, o); }
  const int lane = tid & 63, wv = tid >> 6;
  if (lane == 0) { red[wv] = s; red[wv + 4] = q; }
  __syncthreads();
  const float st = red[0] + red[1] + red[2] + red[3];
  const float qt = red[4] + red[5] + red[6] + red[7];
  const float mu = st * (1.0f / E_DIM);
  const float var = qt * (1.0f / E_DIM) - mu * mu;
  const float rstd = rsqrtf(var + 1e-5f);

  float4 gg = *(const float4*)(g + e);
  float4 bb = *(const float4*)(bta + e);
  float y0 = (x0 - mu) * rstd * gg.x + bb.x;
  float y1 = (x1 - mu) * rstd * gg.y + bb.y;
  float y2 = (x2 - mu) * rstd * gg.z + bb.z;
  float y3 = (x3 - mu) * rstd * gg.w + bb.w;

  us4 ho, lo;
  ho.x = f2bf(y0); lo.x = f2bf(y0 - bf2f(ho.x));
  ho.y = f2bf(y1); lo.y = f2bf(y1 - bf2f(ho.y));
  ho.z = f2bf(y2); lo.z = f2bf(y2 - bf2f(ho.z));
  ho.w = f2bf(y3); lo.w = f2bf(y3 - bf2f(ho.w));
  *(us4*)(hp + e) = ho;
  *(us4*)(lp + e) = lo;
}

// ---------------------------------------------------------------------------
// Embedding: A_emb[b,e] = act[b,:640] @ W_emb[:640, e]
// ---------------------------------------------------------------------------
__global__ __launch_bounds__(256)
void emb_dot(const float* __restrict__ act, const float* __restrict__ Wemb,
             float* __restrict__ Aemb)
{
  const int e = blockIdx.x * 256 + threadIdx.x;
  const int b = blockIdx.y;
  const float* ab = act + b * ACT_D;
  float s = 0.f;
  for (int d = 0; d < ACT_D; d++)
    s = fmaf(ab[d], Wemb[(long long)d * E_DIM + e], s);
  Aemb[b * E_DIM + e] = s;
}

// Hs[b,i,:] = (i even ? A_emb[b] : 0) + b_emb + W_emb[651] + (i+1)*W_emb[652] + wpe[i]
__global__ __launch_bounds__(256)
void emb_fill(const float* __restrict__ Aemb, const float* __restrict__ Wemb,
              const float* __restrict__ bemb, const float* __restrict__ wpe,
              u16* __restrict__ oh, u16* __restrict__ ol)
{
  const int i = blockIdx.x, b = blockIdx.y;
  const int e = threadIdx.x * 4;
  float4 a;
  if ((i & 1) == 0) a = *(const float4*)(Aemb + b * E_DIM + e);
  else { a.x = 0.f; a.y = 0.f; a.z = 0.f; a.w = 0.f; }
  float4 be = *(const float4*)(bemb + e);
  float4 w1 = *(const float4*)(Wemb + 651LL * E_DIM + e);
  float4 w2 = *(const float4*)(Wemb + 652LL * E_DIM + e);
  float4 pw = *(const float4*)(wpe + (long long)i * E_DIM + e);
  const float pos = (float)(i + 1);
  float y0 = a.x + be.x + w1.x + pos * w2.x + pw.x;
  float y1 = a.y + be.y + w1.y + pos * w2.y + pw.y;
  float y2 = a.z + be.z + w1.z + pos * w2.z + pw.z;
  float y3 = a.w + be.w + w1.w + pos * w2.w + pw.w;
  const long long row = (long long)b * N_SEQ + i;

  us4 ho, lo;
  ho.x = f2bf(y0); lo.x = f2bf(y0 - bf2f(ho.x));
  ho.y = f2bf(y1); lo.y = f2bf(y1 - bf2f(ho.y));
  ho.z = f2bf(y2); lo.z = f2bf(y2 - bf2f(ho.z));
  ho.w = f2bf(y3); lo.w = f2bf(y3 - bf2f(ho.w));
  *(us4*)(oh + row * E_DIM + e) = ho;
  *(us4*)(ol + row * E_DIM + e) = lo;
}

// ---------------------------------------------------------------------------
// Final head: out[b,h,:] = (hh+hl)[b,2h,:] @ W_pred + b_pred
// ---------------------------------------------------------------------------
__global__ __launch_bounds__(256)
void pred_k(const u16* __restrict__ hh, const u16* __restrict__ hl,
            const float* __restrict__ Wp, const float* __restrict__ bp,
            float* __restrict__ out)
{
  __shared__ float part[4][ADIM_];
  const int h = blockIdx.x, b = blockIdx.y;
  const long long row = (long long)b * N_SEQ + 2 * h;
  const u16* xh = hh + row * E_DIM;
  const u16* xl = hl + row * E_DIM;
  float acc[ADIM_];
  #pragma unroll
  for (int a = 0; a < ADIM_; a++) acc[a] = 0.f;
  for (int e = threadIdx.x; e < E_DIM; e += 256) {
    const float xv = bf2f(xh[e]) + bf2f(xl[e]);
    const float* wq = Wp + e * ADIM_;
    #pragma unroll
    for (int a = 0; a < ADIM_; a++) acc[a] = fmaf(xv, wq[a], acc[a]);
  }
  const int lane = threadIdx.x & 63, wv = threadIdx.x >> 6;
  #pragma unroll
  for (int a = 0; a < ADIM_; a++)
    #pragma unroll
    for (int o = 32; o > 0; o >>= 1) acc[a] += __shfl_down(acc[a], o);
  if (lane == 0)
    #pragma unroll
    for (int a = 0; a < ADIM_; a++) part[wv][a] = acc[a];
  __syncthreads();
  if (threadIdx.x < ADIM_) {
    const int a = threadIdx.x;
    out[((long long)b * (N_SEQ / 2) + h) * ADIM_ + a] =
        part[0][a] + part[1][a] + part[2][a] + part[3][a] + bp[a];
  }
}

// Diagnostic sentinel: unambiguous "workspace too small" signature
__global__ __launch_bounds__(256)
void fill_sentinel(float* p, int n, float v)
{
  int i = blockIdx.x * 256 + threadIdx.x;
  if (i < n) p[i] = v;
}

// ---------------------------------------------------------------------------
extern "C" void kernel_launch(void* const* d_in, const int* in_sizes, int n_in,
                              void* d_out, int out_size, void* d_ws, size_t ws_size,
                              hipStream_t stream)
{
  const float* act  = (const float*)d_in[0];
  // d_in[1] context_rewards: numerically unused by the reference
  const float* wpe  = (const float*)d_in[2];
  const float* Wemb = (const float*)d_in[3];
  const float* bemb = (const float*)d_in[4];
  const float* Wq   = (const float*)d_in[5];
  const float* Wk   = (const float*)d_in[6];
  const float* Wv   = (const float*)d_in[7];
  const float* ln1g = (const float*)d_in[8];
  const float* ln1b = (const float*)d_in[9];
  const float* W1   = (const float*)d_in[10];
  const float* b1   = (const float*)d_in[11];
  const float* W2   = (const float*)d_in[12];
  const float* b2   = (const float*)d_in[13];
  const float* ln2g = (const float*)d_in[14];
  const float* ln2b = (const float*)d_in[15];
  const float* Wp   = (const float*)d_in[16];
  const float* bp   = (const float*)d_in[17];
  float* out = (float*)d_out;

  const long long sQ = (long long)N_SEQ * E_DIM;   // per-batch elems (= N^2 too)
  const long long sE = (long long)E_DIM * E_DIM;

  // ws: per-batch 16B/elem: hs pair(4) + q pair(4) + kreg(4: k pair | dbuf f32)
  //     + s pair(4); shared: 3 wt pairs (12.6MB) + Aemb
  auto need = [&](int G) -> size_t {
    return (size_t)G * sQ * 16 + (size_t)sE * 12
         + (size_t)G * E_DIM * 4 + (size_t)(1 << 20);
  };
  int G = 16;
  while (G > 1 && need(G) > ws_size) G >>= 1;
  if (need(G) > ws_size || d_ws == nullptr || G < 8) {
    fill_sentinel<<<dim3((out_size + 255) / 256), 256, 0, stream>>>(out, out_size, 1.0e7f);
    return;
  }

  char* ws = (char*)d_ws;
  size_t off = 0;
  auto alloc = [&](size_t bytes) -> void* {
    void* p = ws + off;
    off += (bytes + 255) & ~(size_t)255;
    return p;
  };
  u16* hsh = (u16*)alloc((size_t)G * sQ * 2);
  u16* hsl = (u16*)alloc((size_t)G * sQ * 2);
  u16* qh  = (u16*)alloc((size_t)G * sQ * 2);   // q -> vT -> MLP hidden
  u16* ql  = (u16*)alloc((size_t)G * sQ * 2);
  char* kreg = (char*)alloc((size_t)G * sQ * 4);  // k pair, later dbuf f32
  u16* kh = (u16*)kreg;
  u16* kl = kh + (size_t)G * sQ;
  float* dbuf = (float*)kreg;
  u16* sh_ = (u16*)alloc((size_t)G * sQ * 2);
  u16* sl_ = (u16*)alloc((size_t)G * sQ * 2);
  u16* wAh = (u16*)alloc((size_t)sE * 2);
  u16* wAl = (u16*)alloc((size_t)sE * 2);
  u16* wBh = (u16*)alloc((size_t)sE * 2);
  u16* wBl = (u16*)alloc((size_t)sE * 2);
  u16* wCh = (u16*)alloc((size_t)sE * 2);
  u16* wCl = (u16*)alloc((size_t)sE * 2);
  float* Aemb = (float*)alloc((size_t)G * E_DIM * 4);

  const int tE = E_DIM / BN;                  // 8 col tiles of 128
  const int triS = 20;                        // causal (256r x 128c) tiles
  const dim3 gqk((G * N_SEQ / BM) * tE, 1, 2);   // fused Q+K (batch in M)
  const dim3 gm ((G * N_SEQ / BM) * tE, 1, 1);   // MLP GEMMs
  const dim3 gsq(triS, G, 1);                    // causal S tiles
  const dim3 gv ((N_SEQ / BM) * tE, G, 1);       // vT / S@V (per-batch M=1024)

  for (int g0 = 0; g0 < B_SZ; g0 += G) {
    emb_dot<<<dim3(E_DIM / 256, G), 256, 0, stream>>>(act + (long long)g0 * ACT_D, Wemb, Aemb);
    emb_fill<<<dim3(N_SEQ, G), 256, 0, stream>>>(Aemb, Wemb, bemb, wpe, hsh, hsl);

    for (int l = 0; l < L_NUM; l++) {
      const long long wof = (long long)l * sE;
      const long long bof = (long long)l * E_DIM;

      // Wq,Wk -> wA,wB (hi/lo, transposed)
      TP3 t2 = {Wq + wof, Wk + wof, Wq + wof, wAh, wAl, wBh, wBl, wAh, wAl};
      transpose_split3<<<dim3(32, 32, 2), 256, 0, stream>>>(t2);
      // fused q|k = Hs @ {Wq,Wk}^T -> pairs
      gemm_nt_mfma<0, 1><<<gqk, 512, 0, stream>>>(hsh, hsl, wAh, wAl, wBh, wBl,
          nullptr, qh, ql, kh, kl, nullptr, nullptr,
          E_DIM, E_DIM, E_DIM, E_DIM, tE, 0, 0, 0);

      // Wv,W1,W2 -> wA,wB,wC (runs after QK; stream-serial)
      TP3 t3 = {Wv + wof, W1 + wof, W2 + wof, wAh, wAl, wBh, wBl, wCh, wCl};
      transpose_split3<<<dim3(32, 32, 3), 256, 0, stream>>>(t3);

      // S = relu(q k^T) * causal/(row+1), causal tiles -> pair
      gemm_nt_mfma<1, 3><<<gsq, 512, 0, stream>>>(qh, ql, kh, kl, kh, kl,
          nullptr, sh_, sl_, sh_, sl_, nullptr, nullptr,
          E_DIM, E_DIM, E_DIM, N_SEQ, tE, sQ, sQ, sQ);

      // vT[e][j] = WvT[e][:] . Hs[j][:]  -> q pair (q dead after S)
      gemm_nt_mfma<0, 1><<<gv, 512, 0, stream>>>(wAh, wAl, hsh, hsl, hsh, hsl,
          nullptr, qh, ql, qh, ql, nullptr, nullptr,
          E_DIM, E_DIM, E_DIM, N_SEQ, tE, 0, sQ, sQ);

      // attn delta = S @ v (K capped at diagonal) -> dbuf (over dead k)
      gemm_nt_mfma<2, 0><<<gv, 512, 0, stream>>>(sh_, sl_, qh, ql, qh, ql,
          dbuf, nullptr, nullptr, nullptr, nullptr, nullptr, nullptr,
          N_SEQ, N_SEQ, N_SEQ, E_DIM, tE, sQ, sQ, sQ);

      // Hs = LN1(Hs + delta)
      resid_ln<<<dim3(G * N_SEQ), 256, 0, stream>>>(hsh, hsl, dbuf,
          ln1g + bof, ln1b + bof);

      // MLP: hidden = relu(Hs@W1^T + b1) -> q pair
      gemm_nt_mfma<0, 2><<<gm, 512, 0, stream>>>(hsh, hsl, wBh, wBl, wBh, wBl,
          nullptr, qh, ql, qh, ql, b1 + bof, b1 + bof,
          E_DIM, E_DIM, E_DIM, E_DIM, tE, 0, 0, 0);
      // delta = hidden@W2^T + b2 -> dbuf
      gemm_nt_mfma<0, 4><<<gm, 512, 0, stream>>>(qh, ql, wCh, wCl, wCh, wCl,
          dbuf, nullptr, nullptr, nullptr, nullptr, b2 + bof, b2 + bof,
          E_DIM, E_DIM, E_DIM, E_DIM, tE, 0, 0, 0);

      // Hs = LN2(Hs + delta)
      resid_ln<<<dim3(G * N_SEQ), 256, 0, stream>>>(hsh, hsl, dbuf,
          ln2g + bof, ln2b + bof);
    }

    pred_k<<<dim3(N_SEQ / 2, G), 256, 0, stream>>>(hsh, hsl, Wp, bp,
        out + (long long)g0 * (N_SEQ / 2) * ADIM_);
  }
}

// Round 4
// 8889.925 us; speedup vs baseline: 1.2848x; 1.0376x over previous
//
#include <hip/hip_runtime.h>
#include <stdint.h>
#include <stddef.h>

// Problem constants (test=False shapes)
#define E_DIM 1024
#define B_SZ  16
#define N_SEQ 1024
#define L_NUM 12
#define ACT_D 640   // DIM*ACT_NUM
#define ADIM_ 10

typedef unsigned short u16;
typedef __attribute__((ext_vector_type(8))) short bf16x8;
typedef __attribute__((ext_vector_type(4))) float f32x4;

__device__ __forceinline__ u16 f2bf(float x) {
  union { float f; unsigned int u; } c; c.f = x;
  unsigned int r = c.u + 0x7fffu + ((c.u >> 16) & 1u);
  return (u16)(r >> 16);
}
__device__ __forceinline__ float bf2f(u16 h) {
  union { unsigned int u; float f; } c; c.u = ((unsigned int)h) << 16;
  return c.f;
}

struct us4 { u16 x, y, z, w; };

#define GLD16(gsrc, ldst) __builtin_amdgcn_global_load_lds( \
    (const __attribute__((address_space(1))) void*)(gsrc),  \
    (__attribute__((address_space(3))) void*)(ldst), 16, 0, 0)

// ---------------------------------------------------------------------------
// Error-compensated split-bf16 MFMA NT GEMM — FAT-WAVE-TILE edition.
//   C[M,N] = A[M,K] @ B[N,K]^T  =  Ah@Bh^T + Al@Bh^T + Ah@Bl^T   (fp32 acc)
// Round-3 post-mortem: 128-col tiles are LDS-read-BW co-bound (320B/lane per
// 48 MFMA). Fix = fatter wave tile for register reuse:
//   BNT=256: block 256x256, 8 waves 2x4, wave 128x64 -> 64 FLOP/LDS-byte
//   BNT=128: block 256x128, 8 waves 4x2, wave  64x64 -> 48 FLOP/LDS-byte
// BK=32, 16x16x32 frags, 2 LDS bufs, per step: stage(next) -> compute(cur)
// -> vmcnt(0)+s_barrier (drain is free: loads get the whole compute phase).
// XOR k-chunk swizzle ((row>>1)&3, 16B granule) on global source + ds_read
// offset (linear LDS dest) -> conflict-free (verified rounds 2-3).
// m204 bijective XCD-chunked bid swizzle, tm-major.
// MODE 0: full grid; MODE 1: causal tiles (256r x 128c, BNT=128 only);
// MODE 2: K capped at (tm+1)*256 (causal S@V).
// EPI 0: Co=acc | 1: split->Ch/Cl | 2: split relu(acc+bias) | 3: split
// causal relu(acc)/(row+1) | 4: Co=acc+bias.
// M%256==0; N%BNT==0; K%32==0; K/32>=1.
// ---------------------------------------------------------------------------
#define BM 256
#define BK 32

template<int MODE, int EPI, int BNT>
__global__ __launch_bounds__(512)
void gemm_nt_mfma(const u16* __restrict__ Ah, const u16* __restrict__ Al,
                  const u16* __restrict__ Bh0, const u16* __restrict__ Bl0,
                  const u16* __restrict__ Bh1, const u16* __restrict__ Bl1,
                  float* __restrict__ Co,
                  u16* __restrict__ Ch0, u16* __restrict__ Cl0,
                  u16* __restrict__ Ch1, u16* __restrict__ Cl1,
                  const float* __restrict__ bias0, const float* __restrict__ bias1,
                  int K, int lda, int ldb, int ldc, int tilesN,
                  long long sA, long long sB, long long sC)
{
  constexpr int LA = BM * BK;          // 8192 u16 per A operand tile
  constexpr int LB = BNT * BK;         // 8192 / 4096 u16 per B operand tile
  constexpr int BUFU = 2 * LA + 2 * LB;
  __shared__ u16 smem[2 * BUFU];       // 128 KB / 96 KB

  constexpr int WAVE_R = (BNT == 256) ? 128 : 64;
  constexpr int WGC = BNT / 64;        // waves along N: 4 or 2
  constexpr int MA = WAVE_R / 16;      // A frags per wave: 8 or 4

  const int tid = threadIdx.x;
  const int bat = blockIdx.y;

  const u16* Bh = Bh0; const u16* Bl = Bl0;
  u16* Ch = Ch0; u16* Cl = Cl0;
  const float* bias = bias0;
  if (blockIdx.z) { Bh = Bh1; Bl = Bl1; Ch = Ch1; Cl = Cl1; bias = bias1; }

  Ah += bat * sA; Al += bat * sA;
  Bh += bat * sB; Bl += bat * sB;

  // bijective XCD-aware block swizzle (m204); tm-major downstream
  int bid;
  {
    const int nwg = gridDim.x;
    const int q = nwg >> 3, r = nwg & 7;
    const int xcd = blockIdx.x & 7, off = blockIdx.x >> 3;
    bid = ((xcd < r) ? xcd * (q + 1) : r * (q + 1) + (xcd - r) * q) + off;
  }

  int tm, tn;
  if (MODE == 1) {
    // causal 256r x 128c tiles: tn <= 2*tm+1; start(m) = m*(m+1)
    int t = bid, m = 0;
    while ((m + 1) * (m + 2) <= t) m++;
    tm = m; tn = t - m * (m + 1);
  } else {
    tm = bid / tilesN;
    tn = bid % tilesN;
  }
  int kend = K;
  if (MODE == 2) { int c = (tm + 1) * BM; kend = (c < K) ? c : K; }
  const int nk = kend / BK;

  // ---- staging map: A 1024 chunks (2/thread); B BNT*4 chunks (2 or 1) ----
  const int ca0 = tid, ca1 = tid + 512;
  const int ra0 = ca0 >> 2, ra1 = ca1 >> 2;
  const int pa0 = ((ca0 & 3) ^ ((ra0 >> 1) & 3)) * 8;
  const int pa1 = ((ca1 & 3) ^ ((ra1 >> 1) & 3)) * 8;
  const int cb0 = tid, cb1 = tid + 512;
  const int rb0 = cb0 >> 2, rb1 = cb1 >> 2;
  const int pb0 = ((cb0 & 3) ^ ((rb0 >> 1) & 3)) * 8;
  const int pb1 = ((cb1 & 3) ^ ((rb1 >> 1) & 3)) * 8;

  const u16* gAh0 = Ah + (long long)(tm * BM + ra0) * lda + pa0;
  const u16* gAh1 = Ah + (long long)(tm * BM + ra1) * lda + pa1;
  const u16* gAl0 = Al + (long long)(tm * BM + ra0) * lda + pa0;
  const u16* gAl1 = Al + (long long)(tm * BM + ra1) * lda + pa1;
  const u16* gBh0 = Bh + (long long)(tn * BNT + rb0) * ldb + pb0;
  const u16* gBl0 = Bl + (long long)(tn * BNT + rb0) * ldb + pb0;
  const u16* gBh1 = Bh + (long long)(tn * BNT + rb1) * ldb + pb1;
  const u16* gBl1 = Bl + (long long)(tn * BNT + rb1) * ldb + pb1;
  const int oa0 = ca0 * 8, oa1 = ca1 * 8, ob0 = cb0 * 8, ob1 = cb1 * 8;

  auto stage = [&](int buf) {
    u16* base = smem + buf * BUFU;
    GLD16(gAh0, base + oa0);
    GLD16(gAh1, base + oa1);
    GLD16(gAl0, base + LA + oa0);
    GLD16(gAl1, base + LA + oa1);
    GLD16(gBh0, base + 2 * LA + ob0);
    GLD16(gBl0, base + 2 * LA + LB + ob0);
    if (BNT == 256) {
      GLD16(gBh1, base + 2 * LA + ob1);
      GLD16(gBl1, base + 2 * LA + LB + ob1);
    }
    gAh0 += BK; gAh1 += BK; gAl0 += BK; gAl1 += BK;
    gBh0 += BK; gBl0 += BK;
    if (BNT == 256) { gBh1 += BK; gBl1 += BK; }
  };

  // ---- fragment read offsets (u16 units), matching XOR swizzle ----
  const int lane = tid & 63;
  const int w = tid >> 6;
  const int wr = w / WGC, wc = w % WGC;
  const int fr = lane & 15;
  const int kq = (lane >> 4) * 8;
  const int sa = ((fr >> 1) & 3) << 3;                // XOR on u16-idx bits 3..4
  const int aoff = ((wr * WAVE_R + fr) * BK + kq) ^ sa;
  const int boff = ((wc * 64 + fr) * BK + kq) ^ sa;

  f32x4 acc[MA][4];
  #pragma unroll
  for (int m = 0; m < MA; m++)
    #pragma unroll
    for (int n = 0; n < 4; n++) acc[m][n] = (f32x4){0.f, 0.f, 0.f, 0.f};

  stage(0);
  asm volatile("s_waitcnt vmcnt(0)" ::: "memory");
  __builtin_amdgcn_s_barrier();

  for (int t = 0; t < nk; t++) {
    if (t + 1 < nk) stage((t + 1) & 1);
    const u16* sb = smem + (t & 1) * BUFU;

    bf16x8 ah[MA], al[MA], bh[4], bl[4];
    #pragma unroll
    for (int m = 0; m < MA; m++) ah[m] = *(const bf16x8*)(sb + aoff + m * (16 * BK));
    #pragma unroll
    for (int n = 0; n < 4; n++) bh[n] = *(const bf16x8*)(sb + 2 * LA + boff + n * (16 * BK));
    __builtin_amdgcn_s_setprio(1);
    #pragma unroll
    for (int m = 0; m < MA; m++)
      #pragma unroll
      for (int n = 0; n < 4; n++)
        acc[m][n] = __builtin_amdgcn_mfma_f32_16x16x32_bf16(ah[m], bh[n], acc[m][n], 0, 0, 0);
    __builtin_amdgcn_s_setprio(0);
    #pragma unroll
    for (int m = 0; m < MA; m++) al[m] = *(const bf16x8*)(sb + LA + aoff + m * (16 * BK));
    __builtin_amdgcn_s_setprio(1);
    #pragma unroll
    for (int m = 0; m < MA; m++)
      #pragma unroll
      for (int n = 0; n < 4; n++)
        acc[m][n] = __builtin_amdgcn_mfma_f32_16x16x32_bf16(al[m], bh[n], acc[m][n], 0, 0, 0);
    __builtin_amdgcn_s_setprio(0);
    #pragma unroll
    for (int n = 0; n < 4; n++) bl[n] = *(const bf16x8*)(sb + 2 * LA + LB + boff + n * (16 * BK));
    __builtin_amdgcn_s_setprio(1);
    #pragma unroll
    for (int m = 0; m < MA; m++)
      #pragma unroll
      for (int n = 0; n < 4; n++)
        acc[m][n] = __builtin_amdgcn_mfma_f32_16x16x32_bf16(ah[m], bl[n], acc[m][n], 0, 0, 0);
    __builtin_amdgcn_s_setprio(0);

    if (t + 1 < nk) {
      asm volatile("s_waitcnt vmcnt(0)" ::: "memory");   // ~free: issued 1 phase ago
      __builtin_amdgcn_s_barrier();
    }
  }

  // epilogue: C/D layout col = lane&15, row = (lane>>4)*4 + reg  [m89/m91]
  if (Co) Co += bat * sC;
  if (Ch) { Ch += bat * sC; Cl += bat * sC; }
  #pragma unroll
  for (int m = 0; m < MA; m++) {
    #pragma unroll
    for (int r = 0; r < 4; r++) {
      const long long row = (long long)tm * BM + wr * WAVE_R + m * 16 + (lane >> 4) * 4 + r;
      #pragma unroll
      for (int n = 0; n < 4; n++) {
        const long long col = (long long)tn * BNT + wc * 64 + n * 16 + (lane & 15);
        float v = acc[m][n][r];
        if (EPI == 2) { v += bias[col]; v = v > 0.f ? v : 0.f; }
        if (EPI == 4) { v += bias[col]; }
        if (EPI == 3) {
          v = v > 0.f ? v : 0.f;
          v = (col <= row) ? v / (float)(row + 1) : 0.f;
        }
        const long long idx = row * (long long)ldc + col;
        if (EPI == 0 || EPI == 4) {
          Co[idx] = v;
        } else {
          u16 h = f2bf(v);
          Ch[idx] = h;
          Cl[idx] = f2bf(v - bf2f(h));
        }
      }
    }
  }
}

// ---------------------------------------------------------------------------
// Fused weight transposes: up to 3 E x E fp32 -> bf16 hi/lo (dst = src^T)
// ---------------------------------------------------------------------------
struct TP3 {
  const float* s0; const float* s1; const float* s2;
  u16* h0; u16* l0; u16* h1; u16* l1; u16* h2; u16* l2;
};

__global__ __launch_bounds__(256)
void transpose_split3(TP3 p)
{
  __shared__ float tile[32][33];
  const float* src; u16* dh; u16* dl;
  if (blockIdx.z == 0)      { src = p.s0; dh = p.h0; dl = p.l0; }
  else if (blockIdx.z == 1) { src = p.s1; dh = p.h1; dl = p.l1; }
  else                      { src = p.s2; dh = p.h2; dl = p.l2; }
  const int c0 = blockIdx.x * 32, r0 = blockIdx.y * 32;
  const int tx = threadIdx.x & 31, ty = threadIdx.x >> 5;  // 32x8
  #pragma unroll
  for (int i = ty; i < 32; i += 8)
    tile[i][tx] = src[(long long)(r0 + i) * E_DIM + c0 + tx];
  __syncthreads();
  #pragma unroll
  for (int i = ty; i < 32; i += 8) {
    const float v = tile[tx][i];
    const u16 h = f2bf(v);
    const long long idx = (long long)(c0 + i) * E_DIM + r0 + tx;
    dh[idx] = h;
    dl[idx] = f2bf(v - bf2f(h));
  }
}

// ---------------------------------------------------------------------------
// Residual add + LayerNorm on the bf16-pair residual stream:
//   x = (hh+hl) + delta;  (hh,hl) = split(LN(x)*g + b)
// ---------------------------------------------------------------------------
__global__ __launch_bounds__(256)
void resid_ln(u16* __restrict__ hh, u16* __restrict__ hl,
              const float* __restrict__ delta,
              const float* __restrict__ g, const float* __restrict__ bta)
{
  __shared__ float red[8];
  const long long row = blockIdx.x;
  u16* hp = hh + row * E_DIM;
  u16* lp = hl + row * E_DIM;
  const float* dp = delta + row * E_DIM;
  const int tid = threadIdx.x;
  const int e = tid * 4;

  us4 hv = *(const us4*)(hp + e);
  us4 lv = *(const us4*)(lp + e);
  float4 d = *(const float4*)(dp + e);
  float x0 = bf2f(hv.x) + bf2f(lv.x) + d.x;
  float x1 = bf2f(hv.y) + bf2f(lv.y) + d.y;
  float x2 = bf2f(hv.z) + bf2f(lv.z) + d.z;
  float x3 = bf2f(hv.w) + bf2f(lv.w) + d.w;
  float s = x0 + x1 + x2 + x3;
  float q = x0 * x0 + x1 * x1 + x2 * x2 + x3 * x3;
  #pragma unroll
  for (int o = 32; o > 0; o >>= 1) { s += __shfl_down(s, o); q += __shfl_down(q, o); }
  const int lane = tid & 63, wv = tid >> 6;
  if (lane == 0) { red[wv] = s; red[wv + 4] = q; }
  __syncthreads();
  const float st = red[0] + red[1] + red[2] + red[3];
  const float qt = red[4] + red[5] + red[6] + red[7];
  const float mu = st * (1.0f / E_DIM);
  const float var = qt * (1.0f / E_DIM) - mu * mu;
  const float rstd = rsqrtf(var + 1e-5f);

  float4 gg = *(const float4*)(g + e);
  float4 bb = *(const float4*)(bta + e);
  float y0 = (x0 - mu) * rstd * gg.x + bb.x;
  float y1 = (x1 - mu) * rstd * gg.y + bb.y;
  float y2 = (x2 - mu) * rstd * gg.z + bb.z;
  float y3 = (x3 - mu) * rstd * gg.w + bb.w;

  us4 ho, lo;
  ho.x = f2bf(y0); lo.x = f2bf(y0 - bf2f(ho.x));
  ho.y = f2bf(y1); lo.y = f2bf(y1 - bf2f(ho.y));
  ho.z = f2bf(y2); lo.z = f2bf(y2 - bf2f(ho.z));
  ho.w = f2bf(y3); lo.w = f2bf(y3 - bf2f(ho.w));
  *(us4*)(hp + e) = ho;
  *(us4*)(lp + e) = lo;
}

// ---------------------------------------------------------------------------
// Embedding: A_emb[b,e] = act[b,:640] @ W_emb[:640, e]
// ---------------------------------------------------------------------------
__global__ __launch_bounds__(256)
void emb_dot(const float* __restrict__ act, const float* __restrict__ Wemb,
             float* __restrict__ Aemb)
{
  const int e = blockIdx.x * 256 + threadIdx.x;
  const int b = blockIdx.y;
  const float* ab = act + b * ACT_D;
  float s = 0.f;
  for (int d = 0; d < ACT_D; d++)
    s = fmaf(ab[d], Wemb[(long long)d * E_DIM + e], s);
  Aemb[b * E_DIM + e] = s;
}

// Hs[b,i,:] = (i even ? A_emb[b] : 0) + b_emb + W_emb[651] + (i+1)*W_emb[652] + wpe[i]
__global__ __launch_bounds__(256)
void emb_fill(const float* __restrict__ Aemb, const float* __restrict__ Wemb,
              const float* __restrict__ bemb, const float* __restrict__ wpe,
              u16* __restrict__ oh, u16* __restrict__ ol)
{
  const int i = blockIdx.x, b = blockIdx.y;
  const int e = threadIdx.x * 4;
  float4 a;
  if ((i & 1) == 0) a = *(const float4*)(Aemb + b * E_DIM + e);
  else { a.x = 0.f; a.y = 0.f; a.z = 0.f; a.w = 0.f; }
  float4 be = *(const float4*)(bemb + e);
  float4 w1 = *(const float4*)(Wemb + 651LL * E_DIM + e);
  float4 w2 = *(const float4*)(Wemb + 652LL * E_DIM + e);
  float4 pw = *(const float4*)(wpe + (long long)i * E_DIM + e);
  const float pos = (float)(i + 1);
  float y0 = a.x + be.x + w1.x + pos * w2.x + pw.x;
  float y1 = a.y + be.y + w1.y + pos * w2.y + pw.y;
  float y2 = a.z + be.z + w1.z + pos * w2.z + pw.z;
  float y3 = a.w + be.w + w1.w + pos * w2.w + pw.w;
  const long long row = (long long)b * N_SEQ + i;

  us4 ho, lo;
  ho.x = f2bf(y0); lo.x = f2bf(y0 - bf2f(ho.x));
  ho.y = f2bf(y1); lo.y = f2bf(y1 - bf2f(ho.y));
  ho.z = f2bf(y2); lo.z = f2bf(y2 - bf2f(ho.z));
  ho.w = f2bf(y3); lo.w = f2bf(y3 - bf2f(ho.w));
  *(us4*)(oh + row * E_DIM + e) = ho;
  *(us4*)(ol + row * E_DIM + e) = lo;
}

// ---------------------------------------------------------------------------
// Final head: out[b,h,:] = (hh+hl)[b,2h,:] @ W_pred + b_pred
// ---------------------------------------------------------------------------
__global__ __launch_bounds__(256)
void pred_k(const u16* __restrict__ hh, const u16* __restrict__ hl,
            const float* __restrict__ Wp, const float* __restrict__ bp,
            float* __restrict__ out)
{
  __shared__ float part[4][ADIM_];
  const int h = blockIdx.x, b = blockIdx.y;
  const long long row = (long long)b * N_SEQ + 2 * h;
  const u16* xh = hh + row * E_DIM;
  const u16* xl = hl + row * E_DIM;
  float acc[ADIM_];
  #pragma unroll
  for (int a = 0; a < ADIM_; a++) acc[a] = 0.f;
  for (int e = threadIdx.x; e < E_DIM; e += 256) {
    const float xv = bf2f(xh[e]) + bf2f(xl[e]);
    const float* wq = Wp + e * ADIM_;
    #pragma unroll
    for (int a = 0; a < ADIM_; a++) acc[a] = fmaf(xv, wq[a], acc[a]);
  }
  const int lane = threadIdx.x & 63, wv = threadIdx.x >> 6;
  #pragma unroll
  for (int a = 0; a < ADIM_; a++)
    #pragma unroll
    for (int o = 32; o > 0; o >>= 1) acc[a] += __shfl_down(acc[a], o);
  if (lane == 0)
    #pragma unroll
    for (int a = 0; a < ADIM_; a++) part[wv][a] = acc[a];
  __syncthreads();
  if (threadIdx.x < ADIM_) {
    const int a = threadIdx.x;
    out[((long long)b * (N_SEQ / 2) + h) * ADIM_ + a] =
        part[0][a] + part[1][a] + part[2][a] + part[3][a] + bp[a];
  }
}

// Diagnostic sentinel: unambiguous "workspace too small" signature
__global__ __launch_bounds__(256)
void fill_sentinel(float* p, int n, float v)
{
  int i = blockIdx.x * 256 + threadIdx.x;
  if (i < n) p[i] = v;
}

// ---------------------------------------------------------------------------
extern "C" void kernel_launch(void* const* d_in, const int* in_sizes, int n_in,
                              void* d_out, int out_size, void* d_ws, size_t ws_size,
                              hipStream_t stream)
{
  const float* act  = (const float*)d_in[0];
  // d_in[1] context_rewards: numerically unused by the reference
  const float* wpe  = (const float*)d_in[2];
  const float* Wemb = (const float*)d_in[3];
  const float* bemb = (const float*)d_in[4];
  const float* Wq   = (const float*)d_in[5];
  const float* Wk   = (const float*)d_in[6];
  const float* Wv   = (const float*)d_in[7];
  const float* ln1g = (const float*)d_in[8];
  const float* ln1b = (const float*)d_in[9];
  const float* W1   = (const float*)d_in[10];
  const float* b1   = (const float*)d_in[11];
  const float* W2   = (const float*)d_in[12];
  const float* b2   = (const float*)d_in[13];
  const float* ln2g = (const float*)d_in[14];
  const float* ln2b = (const float*)d_in[15];
  const float* Wp   = (const float*)d_in[16];
  const float* bp   = (const float*)d_in[17];
  float* out = (float*)d_out;

  const long long sQ = (long long)N_SEQ * E_DIM;   // per-batch elems (= N^2 too)
  const long long sE = (long long)E_DIM * E_DIM;

  auto need = [&](int G) -> size_t {
    return (size_t)G * sQ * 16 + (size_t)sE * 12
         + (size_t)G * E_DIM * 4 + (size_t)(1 << 20);
  };
  int G = 16;
  while (G > 1 && need(G) > ws_size) G >>= 1;
  if (need(G) > ws_size || d_ws == nullptr || G < 8) {
    fill_sentinel<<<dim3((out_size + 255) / 256), 256, 0, stream>>>(out, out_size, 1.0e7f);
    return;
  }

  char* ws = (char*)d_ws;
  size_t off = 0;
  auto alloc = [&](size_t bytes) -> void* {
    void* p = ws + off;
    off += (bytes + 255) & ~(size_t)255;
    return p;
  };
  u16* hsh = (u16*)alloc((size_t)G * sQ * 2);
  u16* hsl = (u16*)alloc((size_t)G * sQ * 2);
  u16* qh  = (u16*)alloc((size_t)G * sQ * 2);   // q -> vT -> MLP hidden
  u16* ql  = (u16*)alloc((size_t)G * sQ * 2);
  char* kreg = (char*)alloc((size_t)G * sQ * 4);  // k pair, later dbuf f32
  u16* kh = (u16*)kreg;
  u16* kl = kh + (size_t)G * sQ;
  float* dbuf = (float*)kreg;
  u16* sh_ = (u16*)alloc((size_t)G * sQ * 2);
  u16* sl_ = (u16*)alloc((size_t)G * sQ * 2);
  u16* wAh = (u16*)alloc((size_t)sE * 2);
  u16* wAl = (u16*)alloc((size_t)sE * 2);
  u16* wBh = (u16*)alloc((size_t)sE * 2);
  u16* wBl = (u16*)alloc((size_t)sE * 2);
  u16* wCh = (u16*)alloc((size_t)sE * 2);
  u16* wCl = (u16*)alloc((size_t)sE * 2);
  float* Aemb = (float*)alloc((size_t)G * E_DIM * 4);

  const bool wide = (G >= 16);          // per-batch GEMMs: BN=256 if machine stays full
  const int triS = 20;                  // causal 256r x 128c tiles per batch

  const dim3 gqk((G * N_SEQ / BM) * (E_DIM / 256), 1, 2);       // QKV, BN=256
  const dim3 gsq(triS, G, 1);                                   // S, BN=128
  const dim3 gm256((G * N_SEQ / BM) * (E_DIM / 256), 1, 1);     // MLP BN=256
  const dim3 gm128((G * N_SEQ / BM) * (E_DIM / 128), 1, 1);     // MLP BN=128
  const dim3 gv256((N_SEQ / BM) * (E_DIM / 256), G, 1);         // vT/SV BN=256
  const dim3 gv128((N_SEQ / BM) * (E_DIM / 128), G, 1);         // vT/SV BN=128

  for (int g0 = 0; g0 < B_SZ; g0 += G) {
    emb_dot<<<dim3(E_DIM / 256, G), 256, 0, stream>>>(act + (long long)g0 * ACT_D, Wemb, Aemb);
    emb_fill<<<dim3(N_SEQ, G), 256, 0, stream>>>(Aemb, Wemb, bemb, wpe, hsh, hsl);

    for (int l = 0; l < L_NUM; l++) {
      const long long wof = (long long)l * sE;
      const long long bof = (long long)l * E_DIM;

      // Wq,Wk -> wA,wB (hi/lo, transposed)
      TP3 t2 = {Wq + wof, Wk + wof, Wq + wof, wAh, wAl, wBh, wBl, wAh, wAl};
      transpose_split3<<<dim3(32, 32, 2), 256, 0, stream>>>(t2);
      // fused q|k = Hs @ {Wq,Wk}^T -> pairs  (BN=256, z=2)
      gemm_nt_mfma<0, 1, 256><<<gqk, 512, 0, stream>>>(hsh, hsl, wAh, wAl, wBh, wBl,
          nullptr, qh, ql, kh, kl, nullptr, nullptr,
          E_DIM, E_DIM, E_DIM, E_DIM, E_DIM / 256, 0, 0, 0);

      // Wv,W1,W2 -> wA,wB,wC
      TP3 t3 = {Wv + wof, W1 + wof, W2 + wof, wAh, wAl, wBh, wBl, wCh, wCl};
      transpose_split3<<<dim3(32, 32, 3), 256, 0, stream>>>(t3);

      // S = relu(q k^T) * causal/(row+1), causal tiles -> pair (BN=128)
      gemm_nt_mfma<1, 3, 128><<<gsq, 512, 0, stream>>>(qh, ql, kh, kl, kh, kl,
          nullptr, sh_, sl_, sh_, sl_, nullptr, nullptr,
          E_DIM, E_DIM, E_DIM, N_SEQ, 0, sQ, sQ, sQ);

      // vT[e][j] = WvT[e][:] . Hs[j][:]  -> q pair (q dead after S)
      if (wide)
        gemm_nt_mfma<0, 1, 256><<<gv256, 512, 0, stream>>>(wAh, wAl, hsh, hsl, hsh, hsl,
            nullptr, qh, ql, qh, ql, nullptr, nullptr,
            E_DIM, E_DIM, E_DIM, N_SEQ, E_DIM / 256, 0, sQ, sQ);
      else
        gemm_nt_mfma<0, 1, 128><<<gv128, 512, 0, stream>>>(wAh, wAl, hsh, hsl, hsh, hsl,
            nullptr, qh, ql, qh, ql, nullptr, nullptr,
            E_DIM, E_DIM, E_DIM, N_SEQ, E_DIM / 128, 0, sQ, sQ);

      // attn delta = S @ v (K capped at diagonal) -> dbuf (over dead k)
      if (wide)
        gemm_nt_mfma<2, 0, 256><<<gv256, 512, 0, stream>>>(sh_, sl_, qh, ql, qh, ql,
            dbuf, nullptr, nullptr, nullptr, nullptr, nullptr, nullptr,
            N_SEQ, N_SEQ, N_SEQ, E_DIM, E_DIM / 256, sQ, sQ, sQ);
      else
        gemm_nt_mfma<2, 0, 128><<<gv128, 512, 0, stream>>>(sh_, sl_, qh, ql, qh, ql,
            dbuf, nullptr, nullptr, nullptr, nullptr, nullptr, nullptr,
            N_SEQ, N_SEQ, N_SEQ, E_DIM, E_DIM / 128, sQ, sQ, sQ);

      // Hs = LN1(Hs + delta)
      resid_ln<<<dim3(G * N_SEQ), 256, 0, stream>>>(hsh, hsl, dbuf,
          ln1g + bof, ln1b + bof);

      // MLP: hidden = relu(Hs@W1^T + b1) -> q pair
      if (wide)
        gemm_nt_mfma<0, 2, 256><<<gm256, 512, 0, stream>>>(hsh, hsl, wBh, wBl, wBh, wBl,
            nullptr, qh, ql, qh, ql, b1 + bof, b1 + bof,
            E_DIM, E_DIM, E_DIM, E_DIM, E_DIM / 256, 0, 0, 0);
      else
        gemm_nt_mfma<0, 2, 128><<<gm128, 512, 0, stream>>>(hsh, hsl, wBh, wBl, wBh, wBl,
            nullptr, qh, ql, qh, ql, b1 + bof, b1 + bof,
            E_DIM, E_DIM, E_DIM, E_DIM, E_DIM / 128, 0, 0, 0);
      // delta = hidden@W2^T + b2 -> dbuf
      if (wide)
        gemm_nt_mfma<0, 4, 256><<<gm256, 512, 0, stream>>>(qh, ql, wCh, wCl, wCh, wCl,
            dbuf, nullptr, nullptr, nullptr, nullptr, b2 + bof, b2 + bof,
            E_DIM, E_DIM, E_DIM, E_DIM, E_DIM / 256, 0, 0, 0);
      else
        gemm_nt_mfma<0, 4, 128><<<gm128, 512, 0, stream>>>(qh, ql, wCh, wCl, wCh, wCl,
            dbuf, nullptr, nullptr, nullptr, nullptr, b2 + bof, b2 + bof,
            E_DIM, E_DIM, E_DIM, E_DIM, E_DIM / 128, 0, 0, 0);

      // Hs = LN2(Hs + delta)
      resid_ln<<<dim3(G * N_SEQ), 256, 0, stream>>>(hsh, hsl, dbuf,
          ln2g + bof, ln2b + bof);
    }

    pred_k<<<dim3(N_SEQ / 2, G), 256, 0, stream>>>(hsh, hsl, Wp, bp,
        out + (long long)g0 * (N_SEQ / 2) * ADIM_);
  }
}